// Round 5
// baseline (182.904 us; speedup 1.0000x reference)
//
#include <hip/hip_runtime.h>
#include <math.h>

typedef float f32x4 __attribute__((ext_vector_type(4)));
typedef short bf16x8 __attribute__((ext_vector_type(8)));
typedef unsigned short u16;

#define RBF_DIM 32
#define CUTOFF 5.0f
#define PI_F 3.14159265358979323846f
#define BB 16
#define PP 8000
#define NEE 80

// ws layout (f32-element offsets)
#define CW_OFF      0            // 8000
#define GCW_OFF     8000         // 8000*64
#define AGG_OFF     520000       // 16*80*64 = 81920
#define ZEJW_OFF    601920       // 101*64
#define ZEKW_OFF    608384       // 101*64
#define EFWB_OFF    614848       // 80*64
#define NORM_OFF    619968       // 16
#define AIDX_OFF    619984       // 8000 int
#define ZJA_OFF     627984       // 8000 int
#define ZKA_OFF     635984       // 8000 int
#define BOFF_OFF    643984       // 17 int (unused now, reserved)
#define BCNT_OFF    644004       // 32 int
#define BSUM_OFF    644036       // 512 f32
#define BCNTB_OFF   644548       // 512 int
#define BLKOFF_OFF  645060       // 33 int
#define CHS_OFF     645096       // 266 int chunk start
#define CHC_OFF     645362       // 266 int chunk count
#define CHB_OFF     645628       // 266 int chunk batch
#define NC_OFF      645894       // 1 int
#define W2THI_OFF   645896       // 4096 u16 (pair W2^T hi)
#define W2TLO_OFF   647944
#define W3THI_OFF   649992
#define W3TLO_OFF   652040
// MFMA geom path:
#define PJA_OFF     654088       // 8000 int (compacted path_j)
#define PKA_OFF     662088       // 8000 int
#define CWA_OFF     670088       // 8000 f32 (compacted cw)
#define HHI_OFF     678088       // u16[1024*128] h_flat hi
#define HLO_OFF     743624       // u16[1024*128]
#define GW1JKH_OFF  809160       // u16[256*128]  [hjW;hkW] A-plane hi
#define GW1JKL_OFF  825544
#define GW1RH_OFF   841928       // u16[128*128]  W1rbf^T hi (k 97 pad 128)
#define GW1RL_OFF   850120
#define GW2H_OFF    858312       // u16[128*128]  gm_W2^T hi
#define GW2L_OFF    866504
#define GW3H_OFF    874696       // u16[64*128]   gm_W3^T hi
#define GW3L_OFF    878792
#define HJW_OFF     882888       // f32[1024*128]
#define HKW_OFF     1013960      // f32[1024*128]
// end 1145032 f32 (~4.6 MB)

__device__ __forceinline__ float siluf(float x) { return x / (1.f + __expf(-x)); }
__device__ __forceinline__ float cutoff_fn(float r) {
    return (r < CUTOFF) ? 0.5f * (cosf(PI_F * r / CUTOFF) + 1.f) : 0.f;
}
__device__ __forceinline__ float rbff(float r, int i) {
    r = fminf(r, CUTOFF);
    float a = r * (31.0f / CUTOFF) - (float)i;
    return __expf(-0.5f * a * a);
}
__device__ __forceinline__ u16 f2bf_rne(float x) {
    unsigned u = __float_as_uint(x);
    return (u16)((u + 0x7FFFu + ((u >> 16) & 1u)) >> 16);
}
__device__ __forceinline__ unsigned cvtpk2(float a, float b) {
    unsigned r;
    asm("v_cvt_pk_bf16_f32 %0, %1, %2" : "=v"(r) : "v"(a), "v"(b));
    return r;
}
__device__ __forceinline__ void splitpack8(const float* xs, bf16x8& hi, bf16x8& lo) {
    union { bf16x8 v; unsigned u[4]; } H, L;
    #pragma unroll
    for (int d = 0; d < 4; ++d) {
        float a = xs[2 * d], b = xs[2 * d + 1];
        unsigned h = cvtpk2(a, b);
        float ra = a - __uint_as_float(h << 16);
        float rb = b - __uint_as_float(h & 0xFFFF0000u);
        H.u[d] = h;
        L.u[d] = cvtpk2(ra, rb);
    }
    hi = H.v; lo = L.v;
}

// ---------------- K0a+K1+weight-splits merged (grid 143)
__global__ __launch_bounds__(256) void k0a_k1(
    const float* r0j, const float* r0k, const float* rjk, const int* pbatch,
    const float* z_emb, const float* e_feat, const float* pe_w1, const float* pe_b1,
    const float* pe_w2, const float* pe_w3,
    const float* h_flat, const float* gm_w1, const float* gm_w2, const float* gm_w3,
    float* ws, int* wsi)
{
    __shared__ float cwL[256];
    __shared__ int bL[256];
    __shared__ int redC[256];
    __shared__ float embL[4 * 32];
    int blkAll = blockIdx.x, t = threadIdx.x;
    if (blkAll < 32) {
        int bi = blkAll;
        for (int i = t; i < 2560; i += 256) ws[AGG_OFF + bi*2560 + i] = 0.f;
        int p = bi*250 + t;
        float cw = 0.f; int bin = -1; int valid = 0;
        if (t < 250) {
            cw = cutoff_fn(r0j[p]) * cutoff_fn(r0k[p]) * cutoff_fn(rjk[p]);
            ws[CW_OFF + p] = cw;
            bin = pbatch[p];
            valid = (cw > 0.f) ? 1 : 0;
        }
        cwL[t] = cw; bL[t] = bin; redC[t] = valid;
        __syncthreads();
        if (t < 16) {
            float s = 0.f; int c2 = 0;
            for (int i = 0; i < 256; ++i) {
                bool m = (bL[i] == t);
                s += m ? cwL[i] : 0.f;
                c2 += (m && cwL[i] > 0.f) ? 1 : 0;
            }
            ws[BSUM_OFF + bi*16 + t] = s;
            wsi[BCNTB_OFF + bi*16 + t] = c2;
        }
        __syncthreads();
        for (int s = 128; s > 0; s >>= 1) {
            if (t < s) redC[t] += redC[t + s];
            __syncthreads();
        }
        if (t == 0) wsi[BCNT_OFF + bi] = redC[0];
        return;
    }
    if (blkAll >= 106) {
        int blk = blkAll - 106;
        if (blk < 32) {            // h_flat split
            u16* hh = (u16*)(ws + HHI_OFF);
            u16* hl = (u16*)(ws + HLO_OFF);
            int base = blk * 4096;
            for (int idx = t; idx < 4096; idx += 256) {
                int e = base + idx;
                float v = h_flat[e];
                u16 h = f2bf_rne(v);
                hh[e] = h;
                hl[e] = f2bf_rne(v - __uint_as_float(((unsigned)h) << 16));
            }
        } else if (blk < 34) {     // gm_w1jk^T (256x128)
            u16* wh = (u16*)(ws + GW1JKH_OFF);
            u16* wl = (u16*)(ws + GW1JKL_OFF);
            int base = (blk - 32) * 16384;
            for (int idx = t; idx < 16384; idx += 256) {
                int e = base + idx;
                int m = e >> 7, k = e & 127;
                float v = gm_w1[((m < 128) ? k : (128 + k)) * 128 + (m & 127)];
                u16 h = f2bf_rne(v);
                wh[e] = h;
                wl[e] = f2bf_rne(v - __uint_as_float(((unsigned)h) << 16));
            }
        } else if (blk == 34) {    // gm_w1rbf^T (128x128, k<97)
            u16* wh = (u16*)(ws + GW1RH_OFF);
            u16* wl = (u16*)(ws + GW1RL_OFF);
            for (int e = t; e < 16384; e += 256) {
                int m = e >> 7, k = e & 127;
                float v = (k < 97) ? gm_w1[(256 + k) * 128 + m] : 0.f;
                u16 h = f2bf_rne(v);
                wh[e] = h;
                wl[e] = f2bf_rne(v - __uint_as_float(((unsigned)h) << 16));
            }
        } else if (blk == 35) {    // gm_w2^T
            u16* wh = (u16*)(ws + GW2H_OFF);
            u16* wl = (u16*)(ws + GW2L_OFF);
            for (int e = t; e < 16384; e += 256) {
                int m = e >> 7, k = e & 127;
                float v = gm_w2[k * 128 + m];
                u16 h = f2bf_rne(v);
                wh[e] = h;
                wl[e] = f2bf_rne(v - __uint_as_float(((unsigned)h) << 16));
            }
        } else {                   // gm_w3^T (64x128)
            u16* wh = (u16*)(ws + GW3H_OFF);
            u16* wl = (u16*)(ws + GW3L_OFF);
            for (int e = t; e < 8192; e += 256) {
                int m = e >> 7, k = e & 127;
                float v = gm_w3[k * 64 + m];
                u16 h = f2bf_rne(v);
                wh[e] = h;
                wl[e] = f2bf_rne(v - __uint_as_float(((unsigned)h) << 16));
            }
        }
        return;
    }
    int blk = blkAll - 32;
    if (blk >= 72) {
        const float* W = (blk == 72) ? pe_w2 : pe_w3;
        u16* hiD = (u16*)(ws + ((blk == 72) ? W2THI_OFF : W3THI_OFF));
        u16* loD = (u16*)(ws + ((blk == 72) ? W2TLO_OFF : W3TLO_OFF));
        for (int idx = t; idx < 4096; idx += 256) {
            int k = idx >> 6, n = idx & 63;
            float v = W[idx];
            u16 h = f2bf_rne(v);
            float hf = __uint_as_float(((unsigned)h) << 16);
            hiD[n*64 + k] = h;
            loD[n*64 + k] = f2bf_rne(v - hf);
        }
        return;
    }
    int r0, nrows, wbase;
    const float* src;
    float* dst;
    bool addb = false;
    if (blk < 26)      { r0 = blk * 4;        nrows = 101; src = z_emb;  wbase = 0;  dst = ws + ZEJW_OFF; }
    else if (blk < 52) { r0 = (blk - 26) * 4; nrows = 101; src = z_emb;  wbase = 32; dst = ws + ZEKW_OFF; }
    else               { r0 = (blk - 52) * 4; nrows = NEE; src = e_feat; wbase = 64; dst = ws + EFWB_OFF; addb = true; }
    if (t < 128) {
        int rl = t >> 5, i = t & 31;
        int r = r0 + rl;
        embL[t] = (r < nrows) ? src[r * 32 + i] : 0.f;
    }
    __syncthreads();
    int rl = t >> 6, c = t & 63;
    float acc = addb ? pe_b1[c] : 0.f;
    #pragma unroll
    for (int i = 0; i < 32; ++i)
        acc = fmaf(embL[rl * 32 + i], pe_w1[(wbase + i) * 64 + c], acc);
    int r = r0 + rl;
    if (r < nrows) dst[r * 64 + c] = acc;
}

// ---------------- K0b: parallel scans, norm, chunk table (1 block, 256 thr)
__global__ __launch_bounds__(256) void k0b(float* ws, int* wsi)
{
    __shared__ int bcntL[32];
    __shared__ int cntB[16];
    __shared__ int boff[17];
    __shared__ int chkoff[17];
    int t = threadIdx.x;
    if (t < 16) {
        float s = 0.f;
        #pragma unroll 4
        for (int bi = 0; bi < 32; ++bi) s += ws[BSUM_OFF + bi*16 + t];
        ws[NORM_OFF + t] = s;
    }
    if (t >= 32 && t < 48) {
        int b = t - 32;
        int cb = 0;
        #pragma unroll 4
        for (int bi = 0; bi < 32; ++bi) cb += wsi[BCNTB_OFF + bi*16 + b];
        cntB[b] = cb;
    }
    if (t >= 64 && t < 96) bcntL[t - 64] = wsi[BCNT_OFF + (t - 64)];
    __syncthreads();
    // Hillis-Steele inclusive scan of bcntL (32)
    for (int off = 1; off < 32; off <<= 1) {
        int v = (t < 32 && t >= off) ? bcntL[t - off] : 0;
        __syncthreads();
        if (t < 32) bcntL[t] += v;
        __syncthreads();
    }
    if (t < 32) wsi[BLKOFF_OFF + t] = bcntL[t] - wsi[BCNT_OFF + t];
    if (t == 0) {
        wsi[BLKOFF_OFF + 32] = bcntL[31];
        int bo = 0, co = 0;
        for (int b = 0; b < 16; ++b) {
            boff[b] = bo; chkoff[b] = co;
            bo += cntB[b];
            co += (cntB[b] + 31) >> 5;
        }
        boff[16] = bo; chkoff[16] = co;
        wsi[NC_OFF] = co;
    }
    __syncthreads();
    int NCv = chkoff[16];
    for (int ci = t; ci < NCv; ci += 256) {
        int b = 0;
        while (chkoff[b + 1] <= ci) b++;
        int local = ci - chkoff[b];
        int rem = cntB[b] - local * 32;
        wsi[CHS_OFF + ci] = boff[b] + local * 32;
        wsi[CHC_OFF + ci] = (rem < 32) ? rem : 32;
        wsi[CHB_OFF + ci] = b;
    }
}

// ---------------- K0c (blocks 0..31) + K1b (blocks 32..47) merged
__global__ __launch_bounds__(256) void k0c_k1b(
    const int* pj, const int* pk, const int* zf, float* ws, int* wsi)
{
    __shared__ int sc[256];
    int blk = blockIdx.x, t = threadIdx.x;
    if (blk < 32) {
        int bi = blk;
        int p = bi*250 + t;
        int valid = (t < 250 && ws[CW_OFF + p] > 0.f) ? 1 : 0;
        sc[t] = valid;
        __syncthreads();
        for (int off = 1; off < 256; off <<= 1) {
            int v = (t >= off) ? sc[t - off] : 0;
            __syncthreads();
            sc[t] += v;
            __syncthreads();
        }
        if (valid) {
            int pos = wsi[BLKOFF_OFF + bi] + sc[t] - 1;
            int pjv = pj[p], pkv = pk[p];
            wsi[AIDX_OFF + pos] = p;
            wsi[ZJA_OFF + pos] = zf[pjv];
            wsi[ZKA_OFF + pos] = zf[pkv];
            wsi[PJA_OFF + pos] = pjv;
            wsi[PKA_OFF + pos] = pkv;
            ws[CWA_OFF + pos] = ws[CW_OFF + p];
        }
        return;
    }
    // ---- k1b: hjW/hkW = [W1j;W1k]^T @ h^T via MFMA
    int a0 = (blk - 32) * 64;
    int lane = t & 63, w = t >> 6, c = lane & 15, g = lane >> 4;
    const u16* hh = (const u16*)(ws + HHI_OFF);
    const u16* hl = (const u16*)(ws + HLO_OFF);
    const u16* wh = (const u16*)(ws + GW1JKH_OFF);
    const u16* wl = (const u16*)(ws + GW1JKL_OFF);
    f32x4 acc[4][4];
    #pragma unroll
    for (int i = 0; i < 4; ++i)
        #pragma unroll
        for (int j = 0; j < 4; ++j) acc[i][j] = (f32x4){0.f, 0.f, 0.f, 0.f};
    #pragma unroll 1
    for (int ks = 0; ks < 4; ++ks) {
        bf16x8 Ah[4], Al[4], Bh[4], Bl[4];
        #pragma unroll
        for (int mt = 0; mt < 4; ++mt) {
            int off = (w * 64 + mt * 16 + c) * 128 + ks * 32 + g * 8;
            Ah[mt] = *(const bf16x8*)(wh + off);
            Al[mt] = *(const bf16x8*)(wl + off);
        }
        #pragma unroll
        for (int nt = 0; nt < 4; ++nt) {
            int off = (a0 + nt * 16 + c) * 128 + ks * 32 + g * 8;
            Bh[nt] = *(const bf16x8*)(hh + off);
            Bl[nt] = *(const bf16x8*)(hl + off);
        }
        #pragma unroll
        for (int mt = 0; mt < 4; ++mt)
            #pragma unroll
            for (int nt = 0; nt < 4; ++nt) {
                f32x4 d = acc[mt][nt];
                d = __builtin_amdgcn_mfma_f32_16x16x32_bf16(Ah[mt], Bh[nt], d, 0, 0, 0);
                d = __builtin_amdgcn_mfma_f32_16x16x32_bf16(Ah[mt], Bl[nt], d, 0, 0, 0);
                d = __builtin_amdgcn_mfma_f32_16x16x32_bf16(Al[mt], Bh[nt], d, 0, 0, 0);
                acc[mt][nt] = d;
            }
    }
    float* dst = ws + ((w < 2) ? HJW_OFF : HKW_OFF);
    #pragma unroll
    for (int mt = 0; mt < 4; ++mt)
        #pragma unroll
        for (int nt = 0; nt < 4; ++nt) {
            int m = (w & 1) * 64 + mt * 16 + g * 4;
            int a = a0 + nt * 16 + c;
            *(f32x4*)(dst + a * 128 + m) = acc[mt][nt];
        }
}

// ---------------- K2: geom MLP via MFMA (unchanged from R4)
__global__ __launch_bounds__(256) void k2_geom_mfma(
    const float* r0jG, const float* r0kG, const float* rjkG, const float* cosG,
    const float* b1g, const float* b2g, const float* b3g,
    float* ws, const int* wsi, float* gcw)
{
    __shared__ __align__(16) float sum3L[32 * 128];
    __shared__ __align__(16) u16 rbfH[4096], rbfL[4096];
    __shared__ __align__(16) u16 h1H[4096], h1L[4096];
    __shared__ __align__(16) u16 h2H[4096], h2L[4096];
    __shared__ int pjS[32], pkS[32];
    __shared__ float cwS[32], r0jS[32], r0kS[32], rjkS[32], cosS[32];

    int NC = wsi[NC_OFF];
    int cid = blockIdx.x;
    if (cid >= NC) return;
    int cs = wsi[CHS_OFF + cid], cnt = wsi[CHC_OFF + cid];
    int t = threadIdx.x, lane = t & 63, w = t >> 6, c = lane & 15, g = lane >> 4;

    if (t < 32) {
        int ap = cs + min(t, cnt - 1);
        int a = wsi[AIDX_OFF + ap];
        pjS[t] = wsi[PJA_OFF + ap]; pkS[t] = wsi[PKA_OFF + ap];
        cwS[t] = ws[CWA_OFF + ap];
        r0jS[t] = r0jG[a]; r0kS[t] = r0kG[a]; rjkS[t] = rjkG[a]; cosS[t] = cosG[a];
    }
    __syncthreads();
    {
        int p = t >> 3, kc = (t & 7) * 16;
        const float* rj = ws + HJW_OFF + pjS[p] * 128 + kc;
        const float* rk = ws + HKW_OFF + pkS[p] * 128 + kc;
        #pragma unroll
        for (int q = 0; q < 4; ++q) {
            f32x4 v = *(const f32x4*)(rj + q * 4) + *(const f32x4*)(rk + q * 4);
            *(f32x4*)(sum3L + ((p * 128 + kc + q * 4) ^ ((p & 7) << 2))) = v;
        }
    }
    {
        int p = t >> 3, k0 = (t & 7) * 16;
        float r0jv = r0jS[p], r0kv = r0kS[p], rjkv = rjkS[p], cv = cosS[p];
        #pragma unroll
        for (int hf = 0; hf < 2; ++hf) {
            int kb = k0 + hf * 8;
            float xs[8];
            #pragma unroll
            for (int i = 0; i < 8; ++i) {
                int k = kb + i;
                float v;
                if (k < 32) v = rbff(r0jv, k);
                else if (k < 64) v = rbff(r0kv, k - 32);
                else if (k < 96) v = rbff(rjkv, k - 64);
                else if (k == 96) v = cv;
                else v = 0.f;
                xs[i] = v;
            }
            bf16x8 hi, lo;
            splitpack8(xs, hi, lo);
            int idx = (p * 128 + kb) ^ ((p & 7) << 3);
            *(bf16x8*)(rbfH + idx) = hi;
            *(bf16x8*)(rbfL + idx) = lo;
        }
    }
    __syncthreads();

    const u16* w1h = (const u16*)(ws + GW1RH_OFF);
    const u16* w1l = (const u16*)(ws + GW1RL_OFF);
    const u16* w2h = (const u16*)(ws + GW2H_OFF);
    const u16* w2l = (const u16*)(ws + GW2L_OFF);
    const u16* w3h = (const u16*)(ws + GW3H_OFF);
    const u16* w3l = (const u16*)(ws + GW3L_OFF);

    f32x4 acc[2][2];
    #pragma unroll
    for (int i = 0; i < 2; ++i)
        #pragma unroll
        for (int j = 0; j < 2; ++j) acc[i][j] = (f32x4){0.f, 0.f, 0.f, 0.f};
    #pragma unroll 1
    for (int ks = 0; ks < 4; ++ks) {
        bf16x8 Ah[2], Al[2], Bh[2], Bl[2];
        #pragma unroll
        for (int ml = 0; ml < 2; ++ml) {
            int off = ((w * 2 + ml) * 16 + c) * 128 + ks * 32 + g * 8;
            Ah[ml] = *(const bf16x8*)(w1h + off);
            Al[ml] = *(const bf16x8*)(w1l + off);
        }
        #pragma unroll
        for (int nt = 0; nt < 2; ++nt) {
            int p = nt * 16 + c;
            int idx = (p * 128 + ks * 32 + g * 8) ^ ((p & 7) << 3);
            Bh[nt] = *(const bf16x8*)(rbfH + idx);
            Bl[nt] = *(const bf16x8*)(rbfL + idx);
        }
        #pragma unroll
        for (int ml = 0; ml < 2; ++ml)
            #pragma unroll
            for (int nt = 0; nt < 2; ++nt) {
                f32x4 d = acc[ml][nt];
                d = __builtin_amdgcn_mfma_f32_16x16x32_bf16(Ah[ml], Bh[nt], d, 0, 0, 0);
                d = __builtin_amdgcn_mfma_f32_16x16x32_bf16(Ah[ml], Bl[nt], d, 0, 0, 0);
                d = __builtin_amdgcn_mfma_f32_16x16x32_bf16(Al[ml], Bh[nt], d, 0, 0, 0);
                acc[ml][nt] = d;
            }
    }
    #pragma unroll
    for (int ml = 0; ml < 2; ++ml)
        #pragma unroll
        for (int nt = 0; nt < 2; ++nt) {
            int p = nt * 16 + c;
            int m0 = (w * 2 + ml) * 16 + g * 4;
            f32x4 s = *(const f32x4*)(sum3L + ((p * 128 + m0) ^ ((p & 7) << 2)));
            f32x4 bb = *(const f32x4*)(b1g + m0);
            f32x4 x = acc[ml][nt] + s + bb;
            float v0 = siluf(x[0]), v1 = siluf(x[1]), v2 = siluf(x[2]), v3 = siluf(x[3]);
            unsigned h01 = cvtpk2(v0, v1), h23 = cvtpk2(v2, v3);
            float l0 = v0 - __uint_as_float(h01 << 16);
            float l1 = v1 - __uint_as_float(h01 & 0xFFFF0000u);
            float l2 = v2 - __uint_as_float(h23 << 16);
            float l3 = v3 - __uint_as_float(h23 & 0xFFFF0000u);
            unsigned lo01 = cvtpk2(l0, l1), lo23 = cvtpk2(l2, l3);
            int idx = (p * 128 + m0) ^ ((p & 7) << 3);
            uint2 uh; uh.x = h01; uh.y = h23;
            uint2 ul; ul.x = lo01; ul.y = lo23;
            *(uint2*)(h1H + idx) = uh;
            *(uint2*)(h1L + idx) = ul;
        }
    __syncthreads();

    #pragma unroll
    for (int i = 0; i < 2; ++i)
        #pragma unroll
        for (int j = 0; j < 2; ++j) acc[i][j] = (f32x4){0.f, 0.f, 0.f, 0.f};
    #pragma unroll 1
    for (int ks = 0; ks < 4; ++ks) {
        bf16x8 Ah[2], Al[2], Bh[2], Bl[2];
        #pragma unroll
        for (int ml = 0; ml < 2; ++ml) {
            int off = ((w * 2 + ml) * 16 + c) * 128 + ks * 32 + g * 8;
            Ah[ml] = *(const bf16x8*)(w2h + off);
            Al[ml] = *(const bf16x8*)(w2l + off);
        }
        #pragma unroll
        for (int nt = 0; nt < 2; ++nt) {
            int p = nt * 16 + c;
            int idx = (p * 128 + ks * 32 + g * 8) ^ ((p & 7) << 3);
            Bh[nt] = *(const bf16x8*)(h1H + idx);
            Bl[nt] = *(const bf16x8*)(h1L + idx);
        }
        #pragma unroll
        for (int ml = 0; ml < 2; ++ml)
            #pragma unroll
            for (int nt = 0; nt < 2; ++nt) {
                f32x4 d = acc[ml][nt];
                d = __builtin_amdgcn_mfma_f32_16x16x32_bf16(Ah[ml], Bh[nt], d, 0, 0, 0);
                d = __builtin_amdgcn_mfma_f32_16x16x32_bf16(Ah[ml], Bl[nt], d, 0, 0, 0);
                d = __builtin_amdgcn_mfma_f32_16x16x32_bf16(Al[ml], Bh[nt], d, 0, 0, 0);
                acc[ml][nt] = d;
            }
    }
    #pragma unroll
    for (int ml = 0; ml < 2; ++ml)
        #pragma unroll
        for (int nt = 0; nt < 2; ++nt) {
            int p = nt * 16 + c;
            int m0 = (w * 2 + ml) * 16 + g * 4;
            f32x4 bb = *(const f32x4*)(b2g + m0);
            f32x4 x = acc[ml][nt] + bb;
            float v0 = siluf(x[0]), v1 = siluf(x[1]), v2 = siluf(x[2]), v3 = siluf(x[3]);
            unsigned h01 = cvtpk2(v0, v1), h23 = cvtpk2(v2, v3);
            float l0 = v0 - __uint_as_float(h01 << 16);
            float l1 = v1 - __uint_as_float(h01 & 0xFFFF0000u);
            float l2 = v2 - __uint_as_float(h23 << 16);
            float l3 = v3 - __uint_as_float(h23 & 0xFFFF0000u);
            unsigned lo01 = cvtpk2(l0, l1), lo23 = cvtpk2(l2, l3);
            int idx = (p * 128 + m0) ^ ((p & 7) << 3);
            uint2 uh; uh.x = h01; uh.y = h23;
            uint2 ul; ul.x = lo01; ul.y = lo23;
            *(uint2*)(h2H + idx) = uh;
            *(uint2*)(h2L + idx) = ul;
        }
    __syncthreads();

    f32x4 acc3[2];
    acc3[0] = (f32x4){0.f, 0.f, 0.f, 0.f};
    acc3[1] = (f32x4){0.f, 0.f, 0.f, 0.f};
    #pragma unroll 1
    for (int ks = 0; ks < 4; ++ks) {
        bf16x8 Ah, Al, Bh[2], Bl[2];
        {
            int off = (w * 16 + c) * 128 + ks * 32 + g * 8;
            Ah = *(const bf16x8*)(w3h + off);
            Al = *(const bf16x8*)(w3l + off);
        }
        #pragma unroll
        for (int nt = 0; nt < 2; ++nt) {
            int p = nt * 16 + c;
            int idx = (p * 128 + ks * 32 + g * 8) ^ ((p & 7) << 3);
            Bh[nt] = *(const bf16x8*)(h2H + idx);
            Bl[nt] = *(const bf16x8*)(h2L + idx);
        }
        #pragma unroll
        for (int nt = 0; nt < 2; ++nt) {
            f32x4 d = acc3[nt];
            d = __builtin_amdgcn_mfma_f32_16x16x32_bf16(Ah, Bh[nt], d, 0, 0, 0);
            d = __builtin_amdgcn_mfma_f32_16x16x32_bf16(Ah, Bl[nt], d, 0, 0, 0);
            d = __builtin_amdgcn_mfma_f32_16x16x32_bf16(Al, Bh[nt], d, 0, 0, 0);
            acc3[nt] = d;
        }
    }
    {
        int m0 = w * 16 + g * 4;
        f32x4 bb = *(const f32x4*)(b3g + m0);
        #pragma unroll
        for (int nt = 0; nt < 2; ++nt) {
            int p = nt * 16 + c;
            if (p < cnt) {
                f32x4 o = (acc3[nt] + bb) * cwS[p];
                *(f32x4*)(gcw + (cs + p) * 64 + m0) = o;
            }
        }
    }
}

// ---------------- K3: pair MLP via MFMA — occupancy-optimized
// LDS exactly 40KB: sL 8K + h2buf 16K + a2lL 8K + a3lL 8K -> 4 blocks/CU.
__global__ __launch_bounds__(256, 4) void k3_pair_mfma(
    const float* ws, const int* wsi, const float* gcw, float* agg,
    const float* b2g, const float* b3g)
{
    __shared__ __align__(16) float sL[32 * 64];      // 8KB
    __shared__ __align__(16) u16 h2buf[4][2048];     // 16KB (per wave: hi[0..1023], lo[1024..2047])
    __shared__ __align__(16) u16 a2lL[4096];         // 8KB  W2^T lo plane (swizzled)
    __shared__ __align__(16) u16 a3lL[4096];         // 8KB  W3^T lo plane (swizzled)

    int NC = wsi[NC_OFF];
    int bid = blockIdx.x;
    int cid = bid / 5;
    int et  = bid - cid * 5;
    if (cid >= NC) return;
    int cs  = wsi[CHS_OFF + cid];
    int cnt = wsi[CHC_OFF + cid];
    int bb  = wsi[CHB_OFF + cid];

    int t = threadIdx.x;
    int lane = t & 63, w = t >> 6;
    int c = lane & 15, g = lane >> 4;

    // stage sL (swizzled f32)
    {
        int p = t >> 3, kc = (t & 7) * 8;
        int ap = cs + min(p, cnt - 1);
        int zj = wsi[ZJA_OFF + ap], zk = wsi[ZKA_OFF + ap];
        const f32x4* rj = (const f32x4*)(ws + ZEJW_OFF + zj * 64 + kc);
        const f32x4* rk = (const f32x4*)(ws + ZEKW_OFF + zk * 64 + kc);
        int sw = (p & 7) << 2;
        *(f32x4*)(sL + ((p * 64 + kc) ^ sw))     = rj[0] + rk[0];
        *(f32x4*)(sL + ((p * 64 + kc + 4) ^ sw)) = rj[1] + rk[1];
    }
    // stage lo-planes of W2^T/W3^T into LDS with row-swizzle
    {
        const unsigned* s2 = (const unsigned*)(ws + W2TLO_OFF);
        const unsigned* s3 = (const unsigned*)(ws + W3TLO_OFF);
        unsigned* d2 = (unsigned*)a2lL;
        unsigned* d3 = (unsigned*)a3lL;
        #pragma unroll
        for (int rr = 0; rr < 8; ++rr) {
            int i = rr * 256 + t;
            int sw = ((i >> 5) & 7) << 2;
            d2[i ^ sw] = s2[i];
            d3[i ^ sw] = s3[i];
        }
    }
    // hi-plane A fragments resident in regs
    const u16* w2hi = (const u16*)(ws + W2THI_OFF);
    const u16* w3hi = (const u16*)(ws + W3THI_OFF);
    bf16x8 A2h[4][2], A3h[4][2];
    #pragma unroll
    for (int mt = 0; mt < 4; ++mt)
        #pragma unroll
        for (int ks = 0; ks < 2; ++ks) {
            int off = (mt * 16 + c) * 64 + ks * 32 + g * 8;
            A2h[mt][ks] = *(const bf16x8*)(w2hi + off);
            A3h[mt][ks] = *(const bf16x8*)(w3hi + off);
        }
    __syncthreads();

    u16* myh = h2buf[w];
    u16* myl = h2buf[w] + 1024;
    const float* efp = ws + EFWB_OFF;
    const int aswz = (c & 7) << 3;   // u16-space swizzle for weight-lo / h2buf

    #pragma unroll 1
    for (int ei = 0; ei < 4; ++ei) {
        int e = et * 16 + w * 4 + ei;
        f32x4 acc[4][2];
        #pragma unroll
        for (int mt = 0; mt < 4; ++mt) {
            acc[mt][0] = (f32x4){0.f, 0.f, 0.f, 0.f};
            acc[mt][1] = (f32x4){0.f, 0.f, 0.f, 0.f};
        }
        // ---- layer 2, per-ks B build + 3-pass MFMA
        #pragma unroll
        for (int ks = 0; ks < 2; ++ks) {
            f32x4 e0 = *(const f32x4*)(efp + e * 64 + ks * 32 + g * 8);
            f32x4 e1 = *(const f32x4*)(efp + e * 64 + ks * 32 + g * 8 + 4);
            bf16x8 Bh[2], Bl[2];
            #pragma unroll
            for (int nt = 0; nt < 2; ++nt) {
                int p = nt * 16 + c;
                int sw = (p & 7) << 2;
                int base = p * 64 + ks * 32 + g * 8;
                f32x4 x0 = *(const f32x4*)(sL + (base ^ sw));
                f32x4 x1 = *(const f32x4*)(sL + ((base + 4) ^ sw));
                x0 += e0; x1 += e1;
                float xs[8];
                #pragma unroll
                for (int i = 0; i < 4; ++i) { xs[i] = siluf(x0[i]); xs[4 + i] = siluf(x1[i]); }
                splitpack8(xs, Bh[nt], Bl[nt]);
            }
            #pragma unroll
            for (int mt = 0; mt < 4; ++mt) {
                bf16x8 a2l = *(const bf16x8*)(a2lL + (((mt * 16 + c) * 64 + ks * 32 + g * 8) ^ aswz));
                #pragma unroll
                for (int nt = 0; nt < 2; ++nt) {
                    f32x4 d = acc[mt][nt];
                    d = __builtin_amdgcn_mfma_f32_16x16x32_bf16(A2h[mt][ks], Bh[nt], d, 0, 0, 0);
                    d = __builtin_amdgcn_mfma_f32_16x16x32_bf16(A2h[mt][ks], Bl[nt], d, 0, 0, 0);
                    d = __builtin_amdgcn_mfma_f32_16x16x32_bf16(a2l,         Bh[nt], d, 0, 0, 0);
                    acc[mt][nt] = d;
                }
            }
        }
        // ---- layer 3 per nt-half (h2 roundtrip through 16p buffer), contrib
        float part[16];
        #pragma unroll
        for (int i = 0; i < 16; ++i) part[i] = 0.f;
        #pragma unroll
        for (int nt = 0; nt < 2; ++nt) {
            #pragma unroll
            for (int mt = 0; mt < 4; ++mt) {
                f32x4 b2v = *(const f32x4*)(b2g + mt * 16 + 4 * g);
                f32x4 h = acc[mt][nt] + b2v;
                float v0 = siluf(h[0]), v1 = siluf(h[1]), v2 = siluf(h[2]), v3 = siluf(h[3]);
                unsigned h01 = cvtpk2(v0, v1), h23 = cvtpk2(v2, v3);
                float l0 = v0 - __uint_as_float(h01 << 16);
                float l1 = v1 - __uint_as_float(h01 & 0xFFFF0000u);
                float l2 = v2 - __uint_as_float(h23 << 16);
                float l3 = v3 - __uint_as_float(h23 & 0xFFFF0000u);
                unsigned lo01 = cvtpk2(l0, l1), lo23 = cvtpk2(l2, l3);
                int idx = (c * 64 + mt * 16 + 4 * g) ^ aswz;
                uint2 uh, ul;
                uh.x = h01; uh.y = h23;
                ul.x = lo01; ul.y = lo23;
                *(uint2*)(myh + idx) = uh;
                *(uint2*)(myl + idx) = ul;
                acc[mt][nt] = (f32x4){0.f, 0.f, 0.f, 0.f};   // reuse as L3 accumulator
            }
            #pragma unroll
            for (int ks = 0; ks < 2; ++ks) {
                int idx = (c * 64 + ks * 32 + g * 8) ^ aswz;
                bf16x8 Ch = *(const bf16x8*)(myh + idx);
                bf16x8 Cl = *(const bf16x8*)(myl + idx);
                #pragma unroll
                for (int mt = 0; mt < 4; ++mt) {
                    bf16x8 a3l = *(const bf16x8*)(a3lL + (((mt * 16 + c) * 64 + ks * 32 + g * 8) ^ aswz));
                    f32x4 d = acc[mt][nt];
                    d = __builtin_amdgcn_mfma_f32_16x16x32_bf16(A3h[mt][ks], Ch, d, 0, 0, 0);
                    d = __builtin_amdgcn_mfma_f32_16x16x32_bf16(A3h[mt][ks], Cl, d, 0, 0, 0);
                    d = __builtin_amdgcn_mfma_f32_16x16x32_bf16(a3l,         Ch, d, 0, 0, 0);
                    acc[mt][nt] = d;
                }
            }
            int pl = nt * 16 + c;
            #pragma unroll
            for (int mt = 0; mt < 4; ++mt) {
                f32x4 b3v = *(const f32x4*)(b3g + mt * 16 + 4 * g);
                f32x4 o = acc[mt][nt] + b3v;
                f32x4 gv = (f32x4){0.f, 0.f, 0.f, 0.f};
                if (pl < cnt) gv = *(const f32x4*)(gcw + (cs + pl) * 64 + mt * 16 + 4 * g);
                #pragma unroll
                for (int r = 0; r < 4; ++r) part[mt * 4 + r] += o[r] * gv[r];
            }
        }
        // ---- reduce over the 16 c-lanes via butterfly, 1 atomic per lane
        #pragma unroll
        for (int i = 0; i < 16; ++i) {
            float v = part[i];
            v += __shfl_xor(v, 1, 64);
            v += __shfl_xor(v, 2, 64);
            v += __shfl_xor(v, 4, 64);
            v += __shfl_xor(v, 8, 64);
            part[i] = v;
        }
        int f = (c >> 2) * 16 + g * 4 + (c & 3);
        atomicAdd(agg + (bb * NEE + e) * 64 + f, part[c]);
    }
}

// ---------------- K4: normalize + out MLP (64->128->64)
__global__ __launch_bounds__(256) void k4_out(
    const float* ws, const float* W1, const float* b1,
    const float* W2, const float* b2, float* out)
{
    __shared__ float xT[64][68];
    __shared__ float W1L[64 * 128];
    __shared__ float hTT[128][68];
    __shared__ float W2L[128 * 64];
    __shared__ float normL[16];
    int t = threadIdx.x;
    int gbase = blockIdx.x * 64;
    if (t < 16) normL[t] = 1.f / fmaxf(ws[NORM_OFF + t], 1e-8f);
    for (int idx = t; idx < 8192; idx += 256) { W1L[idx] = W1[idx]; W2L[idx] = W2[idx]; }
    __syncthreads();
    {
        int r = t & 63, cq = t >> 6;
        int gg = gbase + r;
        int b = gg / NEE;
        float rn = normL[b];
        const float* arow = ws + AGG_OFF + gg * 64 + cq * 16;
        #pragma unroll
        for (int q = 0; q < 4; ++q) {
            float4 v = *(const float4*)(arow + q * 4);
            int c = cq * 16 + q * 4;
            xT[c + 0][r] = v.x * rn; xT[c + 1][r] = v.y * rn;
            xT[c + 2][r] = v.z * rn; xT[c + 3][r] = v.w * rn;
        }
    }
    __syncthreads();
    {
        int tcx = t & 15, trx = t >> 4;
        int c0 = tcx * 8, r0 = trx * 4;
        float acc[4][8];
        #pragma unroll
        for (int j = 0; j < 4; ++j)
            #pragma unroll
            for (int q = 0; q < 8; ++q) acc[j][q] = 0.f;
        #pragma unroll 4
        for (int kk = 0; kk < 64; ++kk) {
            float4 x4 = *(const float4*)&xT[kk][r0];
            float4 wa = *(const float4*)&W1L[kk * 128 + c0];
            float4 wb = *(const float4*)&W1L[kk * 128 + c0 + 4];
            float x[4] = {x4.x, x4.y, x4.z, x4.w};
            float w[8] = {wa.x, wa.y, wa.z, wa.w, wb.x, wb.y, wb.z, wb.w};
            #pragma unroll
            for (int j = 0; j < 4; ++j)
                #pragma unroll
                for (int q = 0; q < 8; ++q)
                    acc[j][q] = fmaf(x[j], w[q], acc[j][q]);
        }
        #pragma unroll
        for (int q = 0; q < 8; ++q) {
            float bb = b1[c0 + q];
            float4 v;
            v.x = siluf(acc[0][q] + bb);
            v.y = siluf(acc[1][q] + bb);
            v.z = siluf(acc[2][q] + bb);
            v.w = siluf(acc[3][q] + bb);
            *(float4*)&hTT[c0 + q][r0] = v;
        }
    }
    __syncthreads();
    {
        int tcx = t & 7, trx = t >> 3;
        int c0 = tcx * 8, r0 = trx * 2;
        float acc[2][8];
        #pragma unroll
        for (int j = 0; j < 2; ++j)
            #pragma unroll
            for (int q = 0; q < 8; ++q) acc[j][q] = 0.f;
        #pragma unroll 4
        for (int kk = 0; kk < 128; ++kk) {
            float2 x2 = *(const float2*)&hTT[kk][r0];
            float4 wa = *(const float4*)&W2L[kk * 64 + c0];
            float4 wb = *(const float4*)&W2L[kk * 64 + c0 + 4];
            float w[8] = {wa.x, wa.y, wa.z, wa.w, wb.x, wb.y, wb.z, wb.w};
            #pragma unroll
            for (int q = 0; q < 8; ++q) {
                acc[0][q] = fmaf(x2.x, w[q], acc[0][q]);
                acc[1][q] = fmaf(x2.y, w[q], acc[1][q]);
            }
        }
        int gg = gbase + r0;
        #pragma unroll
        for (int j = 0; j < 2; ++j) {
            float o[8];
            #pragma unroll
            for (int q = 0; q < 8; ++q) o[q] = acc[j][q] + b2[c0 + q];
            *(float4*)&out[(gg + j) * 64 + c0] = make_float4(o[0], o[1], o[2], o[3]);
            *(float4*)&out[(gg + j) * 64 + c0 + 4] = make_float4(o[4], o[5], o[6], o[7]);
        }
    }
}

extern "C" void kernel_launch(void* const* d_in, const int* in_sizes, int n_in,
                              void* d_out, int out_size, void* d_ws, size_t ws_size,
                              hipStream_t stream) {
    (void)in_sizes; (void)n_in; (void)out_size; (void)ws_size;
    const float* h_flat = (const float*)d_in[0];
    const int*   z_flat = (const int*)d_in[1];
    const float* e_feat = (const float*)d_in[2];
    const int*   path_j = (const int*)d_in[3];
    const int*   path_k = (const int*)d_in[4];
    const float* r0j    = (const float*)d_in[5];
    const float* r0k    = (const float*)d_in[6];
    const float* rjk    = (const float*)d_in[7];
    const float* cosang = (const float*)d_in[8];
    const int*   pbatch = (const int*)d_in[9];
    const float* z_emb  = (const float*)d_in[11];
    const float* pe_w1  = (const float*)d_in[12];
    const float* pe_b1  = (const float*)d_in[13];
    const float* pe_w2  = (const float*)d_in[14];
    const float* pe_b2  = (const float*)d_in[15];
    const float* pe_w3  = (const float*)d_in[16];
    const float* pe_b3  = (const float*)d_in[17];
    const float* gm_w1  = (const float*)d_in[18];
    const float* gm_b1  = (const float*)d_in[19];
    const float* gm_w2  = (const float*)d_in[20];
    const float* gm_b2  = (const float*)d_in[21];
    const float* gm_w3  = (const float*)d_in[22];
    const float* gm_b3  = (const float*)d_in[23];
    const float* op_w1  = (const float*)d_in[24];
    const float* op_b1  = (const float*)d_in[25];
    const float* op_w2  = (const float*)d_in[26];
    const float* op_b2  = (const float*)d_in[27];

    float* ws  = (float*)d_ws;
    int*   wsi = (int*)d_ws;
    float* gcw = ws + GCW_OFF;
    float* agg = ws + AGG_OFF;

    hipLaunchKernelGGL(k0a_k1, dim3(143), dim3(256), 0, stream,
                       r0j, r0k, rjk, pbatch,
                       z_emb, e_feat, pe_w1, pe_b1, pe_w2, pe_w3,
                       h_flat, gm_w1, gm_w2, gm_w3, ws, wsi);
    hipLaunchKernelGGL(k0b, dim3(1), dim3(256), 0, stream, ws, wsi);
    hipLaunchKernelGGL(k0c_k1b, dim3(48), dim3(256), 0, stream,
                       path_j, path_k, z_flat, ws, wsi);
    hipLaunchKernelGGL(k2_geom_mfma, dim3(266), dim3(256), 0, stream,
                       r0j, r0k, rjk, cosang,
                       gm_b1, gm_b2, gm_b3, ws, wsi, gcw);
    hipLaunchKernelGGL(k3_pair_mfma, dim3(1330), dim3(256), 0, stream,
                       ws, wsi, gcw, agg, pe_b2, pe_b3);
    hipLaunchKernelGGL(k4_out, dim3(20), dim3(256), 0, stream,
                       ws, op_w1, op_b1, op_w2, op_b2, (float*)d_out);
}

// Round 6
// 144.931 us; speedup vs baseline: 1.2620x; 1.2620x over previous
//
#include <hip/hip_runtime.h>
#include <math.h>

typedef float f32x4 __attribute__((ext_vector_type(4)));
typedef short bf16x8 __attribute__((ext_vector_type(8)));
typedef unsigned short u16;

#define RBF_DIM 32
#define CUTOFF 5.0f
#define PI_F 3.14159265358979323846f
#define BB 16
#define PP 8000
#define NEE 80

// ws layout (f32-element offsets)
#define CW_OFF      0            // 8000
#define GCW_OFF     8000         // 8000*64
#define AGG_OFF     520000       // 16*80*64 = 81920
#define ZEJW_OFF    601920       // 101*64
#define ZEKW_OFF    608384       // 101*64
#define EFWB_OFF    614848       // 80*64
#define NORM_OFF    619968       // 16
#define AIDX_OFF    619984       // 8000 int
#define ZJA_OFF     627984       // 8000 int
#define ZKA_OFF     635984       // 8000 int
#define BOFF_OFF    643984       // 17 int (reserved)
#define BCNT_OFF    644004       // 32 int
#define BSUM_OFF    644036       // 512 f32
#define BCNTB_OFF   644548       // 512 int
#define BLKOFF_OFF  645060       // 33 int
#define CHS_OFF     645096       // 266 int chunk start
#define CHC_OFF     645362       // 266 int chunk count
#define CHB_OFF     645628       // 266 int chunk batch
#define NC_OFF      645894       // 1 int
#define W2THI_OFF   645896       // 4096 u16 (pair W2^T hi)
#define W2TLO_OFF   647944
#define W3THI_OFF   649992
#define W3TLO_OFF   652040
// MFMA geom path:
#define PJA_OFF     654088       // 8000 int (compacted path_j)
#define PKA_OFF     662088       // 8000 int
#define CWA_OFF     670088       // 8000 f32 (compacted cw)
#define HHI_OFF     678088       // u16[1024*128] h_flat hi
#define HLO_OFF     743624       // u16[1024*128]
#define GW1JKH_OFF  809160       // u16[256*128]  [hjW;hkW] A-plane hi
#define GW1JKL_OFF  825544
#define GW1RH_OFF   841928       // u16[128*128]  W1rbf^T hi (k 97 pad 128)
#define GW1RL_OFF   850120
#define GW2H_OFF    858312       // u16[128*128]  gm_W2^T hi
#define GW2L_OFF    866504
#define GW3H_OFF    874696       // u16[64*128]   gm_W3^T hi
#define GW3L_OFF    878792
#define HJW_OFF     882888       // f32[1024*128]
#define HKW_OFF     1013960      // f32[1024*128]
// end 1145032 f32 (~4.6 MB)

__device__ __forceinline__ float siluf(float x) { return x / (1.f + __expf(-x)); }
__device__ __forceinline__ float cutoff_fn(float r) {
    return (r < CUTOFF) ? 0.5f * (cosf(PI_F * r / CUTOFF) + 1.f) : 0.f;
}
__device__ __forceinline__ float rbff(float r, int i) {
    r = fminf(r, CUTOFF);
    float a = r * (31.0f / CUTOFF) - (float)i;
    return __expf(-0.5f * a * a);
}
__device__ __forceinline__ u16 f2bf_rne(float x) {
    unsigned u = __float_as_uint(x);
    return (u16)((u + 0x7FFFu + ((u >> 16) & 1u)) >> 16);
}
__device__ __forceinline__ unsigned cvtpk2(float a, float b) {
    unsigned r;
    asm("v_cvt_pk_bf16_f32 %0, %1, %2" : "=v"(r) : "v"(a), "v"(b));
    return r;
}
__device__ __forceinline__ void splitpack8(const float* xs, bf16x8& hi, bf16x8& lo) {
    union { bf16x8 v; unsigned u[4]; } H, L;
    #pragma unroll
    for (int d = 0; d < 4; ++d) {
        float a = xs[2 * d], b = xs[2 * d + 1];
        unsigned h = cvtpk2(a, b);
        float ra = a - __uint_as_float(h << 16);
        float rb = b - __uint_as_float(h & 0xFFFF0000u);
        H.u[d] = h;
        L.u[d] = cvtpk2(ra, rb);
    }
    hi = H.v; lo = L.v;
}

// ---------------- K0a+K1+weight-splits merged (grid 143)
__global__ __launch_bounds__(256) void k0a_k1(
    const float* r0j, const float* r0k, const float* rjk, const int* pbatch,
    const float* z_emb, const float* e_feat, const float* pe_w1, const float* pe_b1,
    const float* pe_w2, const float* pe_w3,
    const float* h_flat, const float* gm_w1, const float* gm_w2, const float* gm_w3,
    float* ws, int* wsi)
{
    __shared__ float cwL[256];
    __shared__ int bL[256];
    __shared__ int redC[256];
    __shared__ float embL[4 * 32];
    int blkAll = blockIdx.x, t = threadIdx.x;
    if (blkAll < 32) {
        int bi = blkAll;
        for (int i = t; i < 2560; i += 256) ws[AGG_OFF + bi*2560 + i] = 0.f;
        int p = bi*250 + t;
        float cw = 0.f; int bin = -1; int valid = 0;
        if (t < 250) {
            cw = cutoff_fn(r0j[p]) * cutoff_fn(r0k[p]) * cutoff_fn(rjk[p]);
            ws[CW_OFF + p] = cw;
            bin = pbatch[p];
            valid = (cw > 0.f) ? 1 : 0;
        }
        cwL[t] = cw; bL[t] = bin; redC[t] = valid;
        __syncthreads();
        if (t < 16) {
            float s = 0.f; int c2 = 0;
            for (int i = 0; i < 256; ++i) {
                bool m = (bL[i] == t);
                s += m ? cwL[i] : 0.f;
                c2 += (m && cwL[i] > 0.f) ? 1 : 0;
            }
            ws[BSUM_OFF + bi*16 + t] = s;
            wsi[BCNTB_OFF + bi*16 + t] = c2;
        }
        __syncthreads();
        for (int s = 128; s > 0; s >>= 1) {
            if (t < s) redC[t] += redC[t + s];
            __syncthreads();
        }
        if (t == 0) wsi[BCNT_OFF + bi] = redC[0];
        return;
    }
    if (blkAll >= 106) {
        int blk = blkAll - 106;
        if (blk < 32) {            // h_flat split
            u16* hh = (u16*)(ws + HHI_OFF);
            u16* hl = (u16*)(ws + HLO_OFF);
            int base = blk * 4096;
            for (int idx = t; idx < 4096; idx += 256) {
                int e = base + idx;
                float v = h_flat[e];
                u16 h = f2bf_rne(v);
                hh[e] = h;
                hl[e] = f2bf_rne(v - __uint_as_float(((unsigned)h) << 16));
            }
        } else if (blk < 34) {     // gm_w1jk^T (256x128)
            u16* wh = (u16*)(ws + GW1JKH_OFF);
            u16* wl = (u16*)(ws + GW1JKL_OFF);
            int base = (blk - 32) * 16384;
            for (int idx = t; idx < 16384; idx += 256) {
                int e = base + idx;
                int m = e >> 7, k = e & 127;
                float v = gm_w1[((m < 128) ? k : (128 + k)) * 128 + (m & 127)];
                u16 h = f2bf_rne(v);
                wh[e] = h;
                wl[e] = f2bf_rne(v - __uint_as_float(((unsigned)h) << 16));
            }
        } else if (blk == 34) {    // gm_w1rbf^T (128x128, k<97)
            u16* wh = (u16*)(ws + GW1RH_OFF);
            u16* wl = (u16*)(ws + GW1RL_OFF);
            for (int e = t; e < 16384; e += 256) {
                int m = e >> 7, k = e & 127;
                float v = (k < 97) ? gm_w1[(256 + k) * 128 + m] : 0.f;
                u16 h = f2bf_rne(v);
                wh[e] = h;
                wl[e] = f2bf_rne(v - __uint_as_float(((unsigned)h) << 16));
            }
        } else if (blk == 35) {    // gm_w2^T
            u16* wh = (u16*)(ws + GW2H_OFF);
            u16* wl = (u16*)(ws + GW2L_OFF);
            for (int e = t; e < 16384; e += 256) {
                int m = e >> 7, k = e & 127;
                float v = gm_w2[k * 128 + m];
                u16 h = f2bf_rne(v);
                wh[e] = h;
                wl[e] = f2bf_rne(v - __uint_as_float(((unsigned)h) << 16));
            }
        } else {                   // gm_w3^T (64x128)
            u16* wh = (u16*)(ws + GW3H_OFF);
            u16* wl = (u16*)(ws + GW3L_OFF);
            for (int e = t; e < 8192; e += 256) {
                int m = e >> 7, k = e & 127;
                float v = gm_w3[k * 64 + m];
                u16 h = f2bf_rne(v);
                wh[e] = h;
                wl[e] = f2bf_rne(v - __uint_as_float(((unsigned)h) << 16));
            }
        }
        return;
    }
    int blk = blkAll - 32;
    if (blk >= 72) {
        const float* W = (blk == 72) ? pe_w2 : pe_w3;
        u16* hiD = (u16*)(ws + ((blk == 72) ? W2THI_OFF : W3THI_OFF));
        u16* loD = (u16*)(ws + ((blk == 72) ? W2TLO_OFF : W3TLO_OFF));
        for (int idx = t; idx < 4096; idx += 256) {
            int k = idx >> 6, n = idx & 63;
            float v = W[idx];
            u16 h = f2bf_rne(v);
            float hf = __uint_as_float(((unsigned)h) << 16);
            hiD[n*64 + k] = h;
            loD[n*64 + k] = f2bf_rne(v - hf);
        }
        return;
    }
    int r0, nrows, wbase;
    const float* src;
    float* dst;
    bool addb = false;
    if (blk < 26)      { r0 = blk * 4;        nrows = 101; src = z_emb;  wbase = 0;  dst = ws + ZEJW_OFF; }
    else if (blk < 52) { r0 = (blk - 26) * 4; nrows = 101; src = z_emb;  wbase = 32; dst = ws + ZEKW_OFF; }
    else               { r0 = (blk - 52) * 4; nrows = NEE; src = e_feat; wbase = 64; dst = ws + EFWB_OFF; addb = true; }
    if (t < 128) {
        int rl = t >> 5, i = t & 31;
        int r = r0 + rl;
        embL[t] = (r < nrows) ? src[r * 32 + i] : 0.f;
    }
    __syncthreads();
    int rl = t >> 6, c = t & 63;
    float acc = addb ? pe_b1[c] : 0.f;
    #pragma unroll
    for (int i = 0; i < 32; ++i)
        acc = fmaf(embL[rl * 32 + i], pe_w1[(wbase + i) * 64 + c], acc);
    int r = r0 + rl;
    if (r < nrows) dst[r * 64 + c] = acc;
}

// ---------------- K0b: parallel scans, norm, chunk table (1 block, 256 thr)
__global__ __launch_bounds__(256) void k0b(float* ws, int* wsi)
{
    __shared__ int bcntL[32];
    __shared__ int cntB[16];
    __shared__ int boff[17];
    __shared__ int chkoff[17];
    int t = threadIdx.x;
    if (t < 16) {
        float s = 0.f;
        #pragma unroll 4
        for (int bi = 0; bi < 32; ++bi) s += ws[BSUM_OFF + bi*16 + t];
        ws[NORM_OFF + t] = s;
    }
    if (t >= 32 && t < 48) {
        int b = t - 32;
        int cb = 0;
        #pragma unroll 4
        for (int bi = 0; bi < 32; ++bi) cb += wsi[BCNTB_OFF + bi*16 + b];
        cntB[b] = cb;
    }
    if (t >= 64 && t < 96) bcntL[t - 64] = wsi[BCNT_OFF + (t - 64)];
    __syncthreads();
    for (int off = 1; off < 32; off <<= 1) {
        int v = (t < 32 && t >= off) ? bcntL[t - off] : 0;
        __syncthreads();
        if (t < 32) bcntL[t] += v;
        __syncthreads();
    }
    if (t < 32) wsi[BLKOFF_OFF + t] = bcntL[t] - wsi[BCNT_OFF + t];
    if (t == 0) {
        wsi[BLKOFF_OFF + 32] = bcntL[31];
        int bo = 0, co = 0;
        for (int b = 0; b < 16; ++b) {
            boff[b] = bo; chkoff[b] = co;
            bo += cntB[b];
            co += (cntB[b] + 31) >> 5;
        }
        boff[16] = bo; chkoff[16] = co;
        wsi[NC_OFF] = co;
    }
    __syncthreads();
    int NCv = chkoff[16];
    for (int ci = t; ci < NCv; ci += 256) {
        int b = 0;
        while (chkoff[b + 1] <= ci) b++;
        int local = ci - chkoff[b];
        int rem = cntB[b] - local * 32;
        wsi[CHS_OFF + ci] = boff[b] + local * 32;
        wsi[CHC_OFF + ci] = (rem < 32) ? rem : 32;
        wsi[CHB_OFF + ci] = b;
    }
}

// ---------------- K0c (blocks 0..31) + K1b (blocks 32..47) merged
__global__ __launch_bounds__(256) void k0c_k1b(
    const int* pj, const int* pk, const int* zf, float* ws, int* wsi)
{
    __shared__ int sc[256];
    int blk = blockIdx.x, t = threadIdx.x;
    if (blk < 32) {
        int bi = blk;
        int p = bi*250 + t;
        int valid = (t < 250 && ws[CW_OFF + p] > 0.f) ? 1 : 0;
        sc[t] = valid;
        __syncthreads();
        for (int off = 1; off < 256; off <<= 1) {
            int v = (t >= off) ? sc[t - off] : 0;
            __syncthreads();
            sc[t] += v;
            __syncthreads();
        }
        if (valid) {
            int pos = wsi[BLKOFF_OFF + bi] + sc[t] - 1;
            int pjv = pj[p], pkv = pk[p];
            wsi[AIDX_OFF + pos] = p;
            wsi[ZJA_OFF + pos] = zf[pjv];
            wsi[ZKA_OFF + pos] = zf[pkv];
            wsi[PJA_OFF + pos] = pjv;
            wsi[PKA_OFF + pos] = pkv;
            ws[CWA_OFF + pos] = ws[CW_OFF + p];
        }
        return;
    }
    // ---- k1b: hjW/hkW = [W1j;W1k]^T @ h^T via MFMA
    int a0 = (blk - 32) * 64;
    int lane = t & 63, w = t >> 6, c = lane & 15, g = lane >> 4;
    const u16* hh = (const u16*)(ws + HHI_OFF);
    const u16* hl = (const u16*)(ws + HLO_OFF);
    const u16* wh = (const u16*)(ws + GW1JKH_OFF);
    const u16* wl = (const u16*)(ws + GW1JKL_OFF);
    f32x4 acc[4][4];
    #pragma unroll
    for (int i = 0; i < 4; ++i)
        #pragma unroll
        for (int j = 0; j < 4; ++j) acc[i][j] = (f32x4){0.f, 0.f, 0.f, 0.f};
    #pragma unroll 1
    for (int ks = 0; ks < 4; ++ks) {
        bf16x8 Ah[4], Al[4], Bh[4], Bl[4];
        #pragma unroll
        for (int mt = 0; mt < 4; ++mt) {
            int off = (w * 64 + mt * 16 + c) * 128 + ks * 32 + g * 8;
            Ah[mt] = *(const bf16x8*)(wh + off);
            Al[mt] = *(const bf16x8*)(wl + off);
        }
        #pragma unroll
        for (int nt = 0; nt < 4; ++nt) {
            int off = (a0 + nt * 16 + c) * 128 + ks * 32 + g * 8;
            Bh[nt] = *(const bf16x8*)(hh + off);
            Bl[nt] = *(const bf16x8*)(hl + off);
        }
        #pragma unroll
        for (int mt = 0; mt < 4; ++mt)
            #pragma unroll
            for (int nt = 0; nt < 4; ++nt) {
                f32x4 d = acc[mt][nt];
                d = __builtin_amdgcn_mfma_f32_16x16x32_bf16(Ah[mt], Bh[nt], d, 0, 0, 0);
                d = __builtin_amdgcn_mfma_f32_16x16x32_bf16(Ah[mt], Bl[nt], d, 0, 0, 0);
                d = __builtin_amdgcn_mfma_f32_16x16x32_bf16(Al[mt], Bh[nt], d, 0, 0, 0);
                acc[mt][nt] = d;
            }
    }
    float* dst = ws + ((w < 2) ? HJW_OFF : HKW_OFF);
    #pragma unroll
    for (int mt = 0; mt < 4; ++mt)
        #pragma unroll
        for (int nt = 0; nt < 4; ++nt) {
            int m = (w & 1) * 64 + mt * 16 + g * 4;
            int a = a0 + nt * 16 + c;
            *(f32x4*)(dst + a * 128 + m) = acc[mt][nt];
        }
}

// ---------------- K2: geom MLP via MFMA (unchanged)
__global__ __launch_bounds__(256) void k2_geom_mfma(
    const float* r0jG, const float* r0kG, const float* rjkG, const float* cosG,
    const float* b1g, const float* b2g, const float* b3g,
    float* ws, const int* wsi, float* gcw)
{
    __shared__ __align__(16) float sum3L[32 * 128];
    __shared__ __align__(16) u16 rbfH[4096], rbfL[4096];
    __shared__ __align__(16) u16 h1H[4096], h1L[4096];
    __shared__ __align__(16) u16 h2H[4096], h2L[4096];
    __shared__ int pjS[32], pkS[32];
    __shared__ float cwS[32], r0jS[32], r0kS[32], rjkS[32], cosS[32];

    int NC = wsi[NC_OFF];
    int cid = blockIdx.x;
    if (cid >= NC) return;
    int cs = wsi[CHS_OFF + cid], cnt = wsi[CHC_OFF + cid];
    int t = threadIdx.x, lane = t & 63, w = t >> 6, c = lane & 15, g = lane >> 4;

    if (t < 32) {
        int ap = cs + min(t, cnt - 1);
        int a = wsi[AIDX_OFF + ap];
        pjS[t] = wsi[PJA_OFF + ap]; pkS[t] = wsi[PKA_OFF + ap];
        cwS[t] = ws[CWA_OFF + ap];
        r0jS[t] = r0jG[a]; r0kS[t] = r0kG[a]; rjkS[t] = rjkG[a]; cosS[t] = cosG[a];
    }
    __syncthreads();
    {
        int p = t >> 3, kc = (t & 7) * 16;
        const float* rj = ws + HJW_OFF + pjS[p] * 128 + kc;
        const float* rk = ws + HKW_OFF + pkS[p] * 128 + kc;
        #pragma unroll
        for (int q = 0; q < 4; ++q) {
            f32x4 v = *(const f32x4*)(rj + q * 4) + *(const f32x4*)(rk + q * 4);
            *(f32x4*)(sum3L + ((p * 128 + kc + q * 4) ^ ((p & 7) << 2))) = v;
        }
    }
    {
        int p = t >> 3, k0 = (t & 7) * 16;
        float r0jv = r0jS[p], r0kv = r0kS[p], rjkv = rjkS[p], cv = cosS[p];
        #pragma unroll
        for (int hf = 0; hf < 2; ++hf) {
            int kb = k0 + hf * 8;
            float xs[8];
            #pragma unroll
            for (int i = 0; i < 8; ++i) {
                int k = kb + i;
                float v;
                if (k < 32) v = rbff(r0jv, k);
                else if (k < 64) v = rbff(r0kv, k - 32);
                else if (k < 96) v = rbff(rjkv, k - 64);
                else if (k == 96) v = cv;
                else v = 0.f;
                xs[i] = v;
            }
            bf16x8 hi, lo;
            splitpack8(xs, hi, lo);
            int idx = (p * 128 + kb) ^ ((p & 7) << 3);
            *(bf16x8*)(rbfH + idx) = hi;
            *(bf16x8*)(rbfL + idx) = lo;
        }
    }
    __syncthreads();

    const u16* w1h = (const u16*)(ws + GW1RH_OFF);
    const u16* w1l = (const u16*)(ws + GW1RL_OFF);
    const u16* w2h = (const u16*)(ws + GW2H_OFF);
    const u16* w2l = (const u16*)(ws + GW2L_OFF);
    const u16* w3h = (const u16*)(ws + GW3H_OFF);
    const u16* w3l = (const u16*)(ws + GW3L_OFF);

    f32x4 acc[2][2];
    #pragma unroll
    for (int i = 0; i < 2; ++i)
        #pragma unroll
        for (int j = 0; j < 2; ++j) acc[i][j] = (f32x4){0.f, 0.f, 0.f, 0.f};
    #pragma unroll 1
    for (int ks = 0; ks < 4; ++ks) {
        bf16x8 Ah[2], Al[2], Bh[2], Bl[2];
        #pragma unroll
        for (int ml = 0; ml < 2; ++ml) {
            int off = ((w * 2 + ml) * 16 + c) * 128 + ks * 32 + g * 8;
            Ah[ml] = *(const bf16x8*)(w1h + off);
            Al[ml] = *(const bf16x8*)(w1l + off);
        }
        #pragma unroll
        for (int nt = 0; nt < 2; ++nt) {
            int p = nt * 16 + c;
            int idx = (p * 128 + ks * 32 + g * 8) ^ ((p & 7) << 3);
            Bh[nt] = *(const bf16x8*)(rbfH + idx);
            Bl[nt] = *(const bf16x8*)(rbfL + idx);
        }
        #pragma unroll
        for (int ml = 0; ml < 2; ++ml)
            #pragma unroll
            for (int nt = 0; nt < 2; ++nt) {
                f32x4 d = acc[ml][nt];
                d = __builtin_amdgcn_mfma_f32_16x16x32_bf16(Ah[ml], Bh[nt], d, 0, 0, 0);
                d = __builtin_amdgcn_mfma_f32_16x16x32_bf16(Ah[ml], Bl[nt], d, 0, 0, 0);
                d = __builtin_amdgcn_mfma_f32_16x16x32_bf16(Al[ml], Bh[nt], d, 0, 0, 0);
                acc[ml][nt] = d;
            }
    }
    #pragma unroll
    for (int ml = 0; ml < 2; ++ml)
        #pragma unroll
        for (int nt = 0; nt < 2; ++nt) {
            int p = nt * 16 + c;
            int m0 = (w * 2 + ml) * 16 + g * 4;
            f32x4 s = *(const f32x4*)(sum3L + ((p * 128 + m0) ^ ((p & 7) << 2)));
            f32x4 bb = *(const f32x4*)(b1g + m0);
            f32x4 x = acc[ml][nt] + s + bb;
            float v0 = siluf(x[0]), v1 = siluf(x[1]), v2 = siluf(x[2]), v3 = siluf(x[3]);
            unsigned h01 = cvtpk2(v0, v1), h23 = cvtpk2(v2, v3);
            float l0 = v0 - __uint_as_float(h01 << 16);
            float l1 = v1 - __uint_as_float(h01 & 0xFFFF0000u);
            float l2 = v2 - __uint_as_float(h23 << 16);
            float l3 = v3 - __uint_as_float(h23 & 0xFFFF0000u);
            unsigned lo01 = cvtpk2(l0, l1), lo23 = cvtpk2(l2, l3);
            int idx = (p * 128 + m0) ^ ((p & 7) << 3);
            uint2 uh; uh.x = h01; uh.y = h23;
            uint2 ul; ul.x = lo01; ul.y = lo23;
            *(uint2*)(h1H + idx) = uh;
            *(uint2*)(h1L + idx) = ul;
        }
    __syncthreads();

    #pragma unroll
    for (int i = 0; i < 2; ++i)
        #pragma unroll
        for (int j = 0; j < 2; ++j) acc[i][j] = (f32x4){0.f, 0.f, 0.f, 0.f};
    #pragma unroll 1
    for (int ks = 0; ks < 4; ++ks) {
        bf16x8 Ah[2], Al[2], Bh[2], Bl[2];
        #pragma unroll
        for (int ml = 0; ml < 2; ++ml) {
            int off = ((w * 2 + ml) * 16 + c) * 128 + ks * 32 + g * 8;
            Ah[ml] = *(const bf16x8*)(w2h + off);
            Al[ml] = *(const bf16x8*)(w2l + off);
        }
        #pragma unroll
        for (int nt = 0; nt < 2; ++nt) {
            int p = nt * 16 + c;
            int idx = (p * 128 + ks * 32 + g * 8) ^ ((p & 7) << 3);
            Bh[nt] = *(const bf16x8*)(h1H + idx);
            Bl[nt] = *(const bf16x8*)(h1L + idx);
        }
        #pragma unroll
        for (int ml = 0; ml < 2; ++ml)
            #pragma unroll
            for (int nt = 0; nt < 2; ++nt) {
                f32x4 d = acc[ml][nt];
                d = __builtin_amdgcn_mfma_f32_16x16x32_bf16(Ah[ml], Bh[nt], d, 0, 0, 0);
                d = __builtin_amdgcn_mfma_f32_16x16x32_bf16(Ah[ml], Bl[nt], d, 0, 0, 0);
                d = __builtin_amdgcn_mfma_f32_16x16x32_bf16(Al[ml], Bh[nt], d, 0, 0, 0);
                acc[ml][nt] = d;
            }
    }
    #pragma unroll
    for (int ml = 0; ml < 2; ++ml)
        #pragma unroll
        for (int nt = 0; nt < 2; ++nt) {
            int p = nt * 16 + c;
            int m0 = (w * 2 + ml) * 16 + g * 4;
            f32x4 bb = *(const f32x4*)(b2g + m0);
            f32x4 x = acc[ml][nt] + bb;
            float v0 = siluf(x[0]), v1 = siluf(x[1]), v2 = siluf(x[2]), v3 = siluf(x[3]);
            unsigned h01 = cvtpk2(v0, v1), h23 = cvtpk2(v2, v3);
            float l0 = v0 - __uint_as_float(h01 << 16);
            float l1 = v1 - __uint_as_float(h01 & 0xFFFF0000u);
            float l2 = v2 - __uint_as_float(h23 << 16);
            float l3 = v3 - __uint_as_float(h23 & 0xFFFF0000u);
            unsigned lo01 = cvtpk2(l0, l1), lo23 = cvtpk2(l2, l3);
            int idx = (p * 128 + m0) ^ ((p & 7) << 3);
            uint2 uh; uh.x = h01; uh.y = h23;
            uint2 ul; ul.x = lo01; ul.y = lo23;
            *(uint2*)(h2H + idx) = uh;
            *(uint2*)(h2L + idx) = ul;
        }
    __syncthreads();

    f32x4 acc3[2];
    acc3[0] = (f32x4){0.f, 0.f, 0.f, 0.f};
    acc3[1] = (f32x4){0.f, 0.f, 0.f, 0.f};
    #pragma unroll 1
    for (int ks = 0; ks < 4; ++ks) {
        bf16x8 Ah, Al, Bh[2], Bl[2];
        {
            int off = (w * 16 + c) * 128 + ks * 32 + g * 8;
            Ah = *(const bf16x8*)(w3h + off);
            Al = *(const bf16x8*)(w3l + off);
        }
        #pragma unroll
        for (int nt = 0; nt < 2; ++nt) {
            int p = nt * 16 + c;
            int idx = (p * 128 + ks * 32 + g * 8) ^ ((p & 7) << 3);
            Bh[nt] = *(const bf16x8*)(h2H + idx);
            Bl[nt] = *(const bf16x8*)(h2L + idx);
        }
        #pragma unroll
        for (int nt = 0; nt < 2; ++nt) {
            f32x4 d = acc3[nt];
            d = __builtin_amdgcn_mfma_f32_16x16x32_bf16(Ah, Bh[nt], d, 0, 0, 0);
            d = __builtin_amdgcn_mfma_f32_16x16x32_bf16(Ah, Bl[nt], d, 0, 0, 0);
            d = __builtin_amdgcn_mfma_f32_16x16x32_bf16(Al, Bh[nt], d, 0, 0, 0);
            acc3[nt] = d;
        }
    }
    {
        int m0 = w * 16 + g * 4;
        f32x4 bb = *(const f32x4*)(b3g + m0);
        #pragma unroll
        for (int nt = 0; nt < 2; ++nt) {
            int p = nt * 16 + c;
            if (p < cnt) {
                f32x4 o = (acc3[nt] + bb) * cwS[p];
                *(f32x4*)(gcw + (cs + p) * 64 + m0) = o;
            }
        }
    }
}

// ---------------- K3: pair MLP via MFMA — sequential-nt, unforced bounds
// LDS 40960: sL 8K + h2buf 16K + a2lL 8K + a3lL 8K.
// Block = 1 chunk x 20 e-values; wave w -> e = et*20 + w*5 + {0..4}; grid 266*4.
__global__ __launch_bounds__(256) void k3_pair_mfma(
    const float* ws, const int* wsi, const float* gcw, float* agg,
    const float* b2g, const float* b3g)
{
    __shared__ __align__(16) float sL[32 * 64];      // 8KB
    __shared__ __align__(16) u16 h2buf[4][2048];     // 16KB (per wave: hi[0..1023], lo[1024..2047])
    __shared__ __align__(16) u16 a2lL[4096];         // 8KB  W2^T lo plane (swizzled)
    __shared__ __align__(16) u16 a3lL[4096];         // 8KB  W3^T lo plane (swizzled)

    int NC = wsi[NC_OFF];
    int bid = blockIdx.x;
    int cid = bid >> 2;
    int et  = bid & 3;
    if (cid >= NC) return;
    int cs  = wsi[CHS_OFF + cid];
    int cnt = wsi[CHC_OFF + cid];
    int bb  = wsi[CHB_OFF + cid];

    int t = threadIdx.x;
    int lane = t & 63, w = t >> 6;
    int c = lane & 15, g = lane >> 4;

    // stage sL (swizzled f32)
    {
        int p = t >> 3, kc = (t & 7) * 8;
        int ap = cs + min(p, cnt - 1);
        int zj = wsi[ZJA_OFF + ap], zk = wsi[ZKA_OFF + ap];
        const f32x4* rj = (const f32x4*)(ws + ZEJW_OFF + zj * 64 + kc);
        const f32x4* rk = (const f32x4*)(ws + ZEKW_OFF + zk * 64 + kc);
        int sw = (p & 7) << 2;
        *(f32x4*)(sL + ((p * 64 + kc) ^ sw))     = rj[0] + rk[0];
        *(f32x4*)(sL + ((p * 64 + kc + 4) ^ sw)) = rj[1] + rk[1];
    }
    // stage lo-planes of W2^T/W3^T into LDS with row-swizzle
    {
        const unsigned* s2 = (const unsigned*)(ws + W2TLO_OFF);
        const unsigned* s3 = (const unsigned*)(ws + W3TLO_OFF);
        unsigned* d2 = (unsigned*)a2lL;
        unsigned* d3 = (unsigned*)a3lL;
        #pragma unroll
        for (int rr = 0; rr < 8; ++rr) {
            int i = rr * 256 + t;
            int sw = ((i >> 5) & 7) << 2;
            d2[i ^ sw] = s2[i];
            d3[i ^ sw] = s3[i];
        }
    }
    // hi-plane A fragments resident in regs
    const u16* w2hi = (const u16*)(ws + W2THI_OFF);
    const u16* w3hi = (const u16*)(ws + W3THI_OFF);
    bf16x8 A2h[4][2], A3h[4][2];
    #pragma unroll
    for (int mt = 0; mt < 4; ++mt)
        #pragma unroll
        for (int ks = 0; ks < 2; ++ks) {
            int off = (mt * 16 + c) * 64 + ks * 32 + g * 8;
            A2h[mt][ks] = *(const bf16x8*)(w2hi + off);
            A3h[mt][ks] = *(const bf16x8*)(w3hi + off);
        }
    __syncthreads();

    u16* myh = h2buf[w];
    u16* myl = h2buf[w] + 1024;
    const float* efp = ws + EFWB_OFF;
    const int aswz = (c & 7) << 3;   // u16-space swizzle for weight-lo / h2buf

    #pragma unroll 1
    for (int ei = 0; ei < 5; ++ei) {
        int e = et * 20 + w * 5 + ei;
        float part[16];
        #pragma unroll
        for (int i = 0; i < 16; ++i) part[i] = 0.f;

        #pragma unroll 1
        for (int nt = 0; nt < 2; ++nt) {
            int p = nt * 16 + c;
            int psw = (p & 7) << 2;
            f32x4 acc4[4];
            #pragma unroll
            for (int mt = 0; mt < 4; ++mt) acc4[mt] = (f32x4){0.f, 0.f, 0.f, 0.f};
            // ---- layer 2
            #pragma unroll
            for (int ks = 0; ks < 2; ++ks) {
                f32x4 e0 = *(const f32x4*)(efp + e * 64 + ks * 32 + g * 8);
                f32x4 e1 = *(const f32x4*)(efp + e * 64 + ks * 32 + g * 8 + 4);
                int base = p * 64 + ks * 32 + g * 8;
                f32x4 x0 = *(const f32x4*)(sL + (base ^ psw));
                f32x4 x1 = *(const f32x4*)(sL + ((base + 4) ^ psw));
                x0 += e0; x1 += e1;
                float xs[8];
                #pragma unroll
                for (int i = 0; i < 4; ++i) { xs[i] = siluf(x0[i]); xs[4 + i] = siluf(x1[i]); }
                bf16x8 Bh, Bl;
                splitpack8(xs, Bh, Bl);
                #pragma unroll
                for (int mt = 0; mt < 4; ++mt) {
                    bf16x8 a2l = *(const bf16x8*)(a2lL + (((mt * 16 + c) * 64 + ks * 32 + g * 8) ^ aswz));
                    f32x4 d = acc4[mt];
                    d = __builtin_amdgcn_mfma_f32_16x16x32_bf16(A2h[mt][ks], Bh, d, 0, 0, 0);
                    d = __builtin_amdgcn_mfma_f32_16x16x32_bf16(A2h[mt][ks], Bl, d, 0, 0, 0);
                    d = __builtin_amdgcn_mfma_f32_16x16x32_bf16(a2l,         Bh, d, 0, 0, 0);
                    acc4[mt] = d;
                }
            }
            // ---- h2 = silu(acc+b2) -> per-wave LDS roundtrip (bf16 hi/lo)
            #pragma unroll
            for (int mt = 0; mt < 4; ++mt) {
                f32x4 b2v = *(const f32x4*)(b2g + mt * 16 + 4 * g);
                f32x4 h = acc4[mt] + b2v;
                float v0 = siluf(h[0]), v1 = siluf(h[1]), v2 = siluf(h[2]), v3 = siluf(h[3]);
                unsigned h01 = cvtpk2(v0, v1), h23 = cvtpk2(v2, v3);
                float l0 = v0 - __uint_as_float(h01 << 16);
                float l1 = v1 - __uint_as_float(h01 & 0xFFFF0000u);
                float l2 = v2 - __uint_as_float(h23 << 16);
                float l3 = v3 - __uint_as_float(h23 & 0xFFFF0000u);
                unsigned lo01 = cvtpk2(l0, l1), lo23 = cvtpk2(l2, l3);
                int idx = (c * 64 + mt * 16 + 4 * g) ^ aswz;
                uint2 uh, ul;
                uh.x = h01; uh.y = h23;
                ul.x = lo01; ul.y = lo23;
                *(uint2*)(myh + idx) = uh;
                *(uint2*)(myl + idx) = ul;
                acc4[mt] = (f32x4){0.f, 0.f, 0.f, 0.f};   // reuse as L3 accumulator
            }
            // ---- layer 3
            #pragma unroll
            for (int ks = 0; ks < 2; ++ks) {
                int idx = (c * 64 + ks * 32 + g * 8) ^ aswz;
                bf16x8 Ch = *(const bf16x8*)(myh + idx);
                bf16x8 Cl = *(const bf16x8*)(myl + idx);
                #pragma unroll
                for (int mt = 0; mt < 4; ++mt) {
                    bf16x8 a3l = *(const bf16x8*)(a3lL + (((mt * 16 + c) * 64 + ks * 32 + g * 8) ^ aswz));
                    f32x4 d = acc4[mt];
                    d = __builtin_amdgcn_mfma_f32_16x16x32_bf16(A3h[mt][ks], Ch, d, 0, 0, 0);
                    d = __builtin_amdgcn_mfma_f32_16x16x32_bf16(A3h[mt][ks], Cl, d, 0, 0, 0);
                    d = __builtin_amdgcn_mfma_f32_16x16x32_bf16(a3l,         Ch, d, 0, 0, 0);
                    acc4[mt] = d;
                }
            }
            // ---- contrib
            #pragma unroll
            for (int mt = 0; mt < 4; ++mt) {
                f32x4 b3v = *(const f32x4*)(b3g + mt * 16 + 4 * g);
                f32x4 o = acc4[mt] + b3v;
                f32x4 gv = (f32x4){0.f, 0.f, 0.f, 0.f};
                if (p < cnt) gv = *(const f32x4*)(gcw + (cs + p) * 64 + mt * 16 + 4 * g);
                #pragma unroll
                for (int r = 0; r < 4; ++r) part[mt * 4 + r] += o[r] * gv[r];
            }
        }
        // ---- reduce over the 16 c-lanes via butterfly, 1 atomic per lane
        #pragma unroll
        for (int i = 0; i < 16; ++i) {
            float v = part[i];
            v += __shfl_xor(v, 1, 64);
            v += __shfl_xor(v, 2, 64);
            v += __shfl_xor(v, 4, 64);
            v += __shfl_xor(v, 8, 64);
            part[i] = v;
        }
        int f = (c >> 2) * 16 + g * 4 + (c & 3);
        atomicAdd(agg + (bb * NEE + e) * 64 + f, part[c]);
    }
}

// ---------------- K4: normalize + out MLP (64->128->64)
__global__ __launch_bounds__(256) void k4_out(
    const float* ws, const float* W1, const float* b1,
    const float* W2, const float* b2, float* out)
{
    __shared__ float xT[64][68];
    __shared__ float W1L[64 * 128];
    __shared__ float hTT[128][68];
    __shared__ float W2L[128 * 64];
    __shared__ float normL[16];
    int t = threadIdx.x;
    int gbase = blockIdx.x * 64;
    if (t < 16) normL[t] = 1.f / fmaxf(ws[NORM_OFF + t], 1e-8f);
    for (int idx = t; idx < 8192; idx += 256) { W1L[idx] = W1[idx]; W2L[idx] = W2[idx]; }
    __syncthreads();
    {
        int r = t & 63, cq = t >> 6;
        int gg = gbase + r;
        int b = gg / NEE;
        float rn = normL[b];
        const float* arow = ws + AGG_OFF + gg * 64 + cq * 16;
        #pragma unroll
        for (int q = 0; q < 4; ++q) {
            float4 v = *(const float4*)(arow + q * 4);
            int c = cq * 16 + q * 4;
            xT[c + 0][r] = v.x * rn; xT[c + 1][r] = v.y * rn;
            xT[c + 2][r] = v.z * rn; xT[c + 3][r] = v.w * rn;
        }
    }
    __syncthreads();
    {
        int tcx = t & 15, trx = t >> 4;
        int c0 = tcx * 8, r0 = trx * 4;
        float acc[4][8];
        #pragma unroll
        for (int j = 0; j < 4; ++j)
            #pragma unroll
            for (int q = 0; q < 8; ++q) acc[j][q] = 0.f;
        #pragma unroll 4
        for (int kk = 0; kk < 64; ++kk) {
            float4 x4 = *(const float4*)&xT[kk][r0];
            float4 wa = *(const float4*)&W1L[kk * 128 + c0];
            float4 wb = *(const float4*)&W1L[kk * 128 + c0 + 4];
            float x[4] = {x4.x, x4.y, x4.z, x4.w};
            float w[8] = {wa.x, wa.y, wa.z, wa.w, wb.x, wb.y, wb.z, wb.w};
            #pragma unroll
            for (int j = 0; j < 4; ++j)
                #pragma unroll
                for (int q = 0; q < 8; ++q)
                    acc[j][q] = fmaf(x[j], w[q], acc[j][q]);
        }
        #pragma unroll
        for (int q = 0; q < 8; ++q) {
            float bb = b1[c0 + q];
            float4 v;
            v.x = siluf(acc[0][q] + bb);
            v.y = siluf(acc[1][q] + bb);
            v.z = siluf(acc[2][q] + bb);
            v.w = siluf(acc[3][q] + bb);
            *(float4*)&hTT[c0 + q][r0] = v;
        }
    }
    __syncthreads();
    {
        int tcx = t & 7, trx = t >> 3;
        int c0 = tcx * 8, r0 = trx * 2;
        float acc[2][8];
        #pragma unroll
        for (int j = 0; j < 2; ++j)
            #pragma unroll
            for (int q = 0; q < 8; ++q) acc[j][q] = 0.f;
        #pragma unroll 4
        for (int kk = 0; kk < 128; ++kk) {
            float2 x2 = *(const float2*)&hTT[kk][r0];
            float4 wa = *(const float4*)&W2L[kk * 64 + c0];
            float4 wb = *(const float4*)&W2L[kk * 64 + c0 + 4];
            float w[8] = {wa.x, wa.y, wa.z, wa.w, wb.x, wb.y, wb.z, wb.w};
            #pragma unroll
            for (int q = 0; q < 8; ++q) {
                acc[0][q] = fmaf(x2.x, w[q], acc[0][q]);
                acc[1][q] = fmaf(x2.y, w[q], acc[1][q]);
            }
        }
        int gg = gbase + r0;
        #pragma unroll
        for (int j = 0; j < 2; ++j) {
            float o[8];
            #pragma unroll
            for (int q = 0; q < 8; ++q) o[q] = acc[j][q] + b2[c0 + q];
            *(float4*)&out[(gg + j) * 64 + c0] = make_float4(o[0], o[1], o[2], o[3]);
            *(float4*)&out[(gg + j) * 64 + c0 + 4] = make_float4(o[4], o[5], o[6], o[7]);
        }
    }
}

extern "C" void kernel_launch(void* const* d_in, const int* in_sizes, int n_in,
                              void* d_out, int out_size, void* d_ws, size_t ws_size,
                              hipStream_t stream) {
    (void)in_sizes; (void)n_in; (void)out_size; (void)ws_size;
    const float* h_flat = (const float*)d_in[0];
    const int*   z_flat = (const int*)d_in[1];
    const float* e_feat = (const float*)d_in[2];
    const int*   path_j = (const int*)d_in[3];
    const int*   path_k = (const int*)d_in[4];
    const float* r0j    = (const float*)d_in[5];
    const float* r0k    = (const float*)d_in[6];
    const float* rjk    = (const float*)d_in[7];
    const float* cosang = (const float*)d_in[8];
    const int*   pbatch = (const int*)d_in[9];
    const float* z_emb  = (const float*)d_in[11];
    const float* pe_w1  = (const float*)d_in[12];
    const float* pe_b1  = (const float*)d_in[13];
    const float* pe_w2  = (const float*)d_in[14];
    const float* pe_b2  = (const float*)d_in[15];
    const float* pe_w3  = (const float*)d_in[16];
    const float* pe_b3  = (const float*)d_in[17];
    const float* gm_w1  = (const float*)d_in[18];
    const float* gm_b1  = (const float*)d_in[19];
    const float* gm_w2  = (const float*)d_in[20];
    const float* gm_b2  = (const float*)d_in[21];
    const float* gm_w3  = (const float*)d_in[22];
    const float* gm_b3  = (const float*)d_in[23];
    const float* op_w1  = (const float*)d_in[24];
    const float* op_b1  = (const float*)d_in[25];
    const float* op_w2  = (const float*)d_in[26];
    const float* op_b2  = (const float*)d_in[27];

    float* ws  = (float*)d_ws;
    int*   wsi = (int*)d_ws;
    float* gcw = ws + GCW_OFF;
    float* agg = ws + AGG_OFF;

    hipLaunchKernelGGL(k0a_k1, dim3(143), dim3(256), 0, stream,
                       r0j, r0k, rjk, pbatch,
                       z_emb, e_feat, pe_w1, pe_b1, pe_w2, pe_w3,
                       h_flat, gm_w1, gm_w2, gm_w3, ws, wsi);
    hipLaunchKernelGGL(k0b, dim3(1), dim3(256), 0, stream, ws, wsi);
    hipLaunchKernelGGL(k0c_k1b, dim3(48), dim3(256), 0, stream,
                       path_j, path_k, z_flat, ws, wsi);
    hipLaunchKernelGGL(k2_geom_mfma, dim3(266), dim3(256), 0, stream,
                       r0j, r0k, rjk, cosang,
                       gm_b1, gm_b2, gm_b3, ws, wsi, gcw);
    hipLaunchKernelGGL(k3_pair_mfma, dim3(1064), dim3(256), 0, stream,
                       ws, wsi, gcw, agg, pe_b2, pe_b3);
    hipLaunchKernelGGL(k4_out, dim3(20), dim3(256), 0, stream,
                       ws, op_w1, op_b1, op_w2, op_b2, (float*)d_out);
}

// Round 7
// 133.937 us; speedup vs baseline: 1.3656x; 1.0821x over previous
//
#include <hip/hip_runtime.h>
#include <math.h>

typedef float f32x4 __attribute__((ext_vector_type(4)));
typedef short bf16x8 __attribute__((ext_vector_type(8)));
typedef unsigned short u16;

#define RBF_DIM 32
#define CUTOFF 5.0f
#define PI_F 3.14159265358979323846f
#define BB 16
#define PP 8000
#define NEE 80

// ws layout (f32-element offsets)
#define CW_OFF      0            // 8000
#define GCW_OFF     8000         // 8000*64
#define AGG_OFF     520000       // 16*80*64 = 81920
#define ZEJW_OFF    601920       // 101*64
#define ZEKW_OFF    608384       // 101*64
#define EFWB_OFF    614848       // 80*64
#define NORM_OFF    619968       // 16
#define AIDX_OFF    619984       // 8000 int
#define ZJA_OFF     627984       // 8000 int
#define ZKA_OFF     635984       // 8000 int
#define BOFF_OFF    643984       // 17 int (reserved)
#define BCNT_OFF    644004       // 32 int
#define BSUM_OFF    644036       // 512 f32
#define BCNTB_OFF   644548       // 512 int
#define BLKOFF_OFF  645060       // 33 int
#define CHS_OFF     645096       // 266 int chunk start
#define CHC_OFF     645362       // 266 int chunk count
#define CHB_OFF     645628       // 266 int chunk batch
#define NC_OFF      645894       // 1 int
#define W2THI_OFF   645896       // 4096 u16 (pair W2^T hi)
#define W2TLO_OFF   647944
#define W3THI_OFF   649992
#define W3TLO_OFF   652040
// MFMA geom path:
#define PJA_OFF     654088       // 8000 int (compacted path_j)
#define PKA_OFF     662088       // 8000 int
#define CWA_OFF     670088       // 8000 f32 (compacted cw)
#define HHI_OFF     678088       // u16[1024*128] h_flat hi
#define HLO_OFF     743624       // u16[1024*128]
#define GW1JKH_OFF  809160       // u16[256*128]  [hjW;hkW] A-plane hi
#define GW1JKL_OFF  825544
#define GW1RH_OFF   841928       // u16[128*128]  W1rbf^T hi (k 97 pad 128)
#define GW1RL_OFF   850120
#define GW2H_OFF    858312       // u16[128*128]  gm_W2^T hi
#define GW2L_OFF    866504
#define GW3H_OFF    874696       // u16[64*128]   gm_W3^T hi
#define GW3L_OFF    878792
#define HJW_OFF     882888       // f32[1024*128]
#define HKW_OFF     1013960      // f32[1024*128]
// end 1145032 f32 (~4.6 MB)

__device__ __forceinline__ float siluf(float x) { return x / (1.f + __expf(-x)); }
__device__ __forceinline__ float cutoff_fn(float r) {
    return (r < CUTOFF) ? 0.5f * (cosf(PI_F * r / CUTOFF) + 1.f) : 0.f;
}
__device__ __forceinline__ float rbff(float r, int i) {
    r = fminf(r, CUTOFF);
    float a = r * (31.0f / CUTOFF) - (float)i;
    return __expf(-0.5f * a * a);
}
__device__ __forceinline__ u16 f2bf_rne(float x) {
    unsigned u = __float_as_uint(x);
    return (u16)((u + 0x7FFFu + ((u >> 16) & 1u)) >> 16);
}
__device__ __forceinline__ unsigned cvtpk2(float a, float b) {
    unsigned r;
    asm("v_cvt_pk_bf16_f32 %0, %1, %2" : "=v"(r) : "v"(a), "v"(b));
    return r;
}
__device__ __forceinline__ void splitpack8(const float* xs, bf16x8& hi, bf16x8& lo) {
    union { bf16x8 v; unsigned u[4]; } H, L;
    #pragma unroll
    for (int d = 0; d < 4; ++d) {
        float a = xs[2 * d], b = xs[2 * d + 1];
        unsigned h = cvtpk2(a, b);
        float ra = a - __uint_as_float(h << 16);
        float rb = b - __uint_as_float(h & 0xFFFF0000u);
        H.u[d] = h;
        L.u[d] = cvtpk2(ra, rb);
    }
    hi = H.v; lo = L.v;
}

// ---------------- K0a+K1+weight-splits merged (grid 143)
__global__ __launch_bounds__(256) void k0a_k1(
    const float* r0j, const float* r0k, const float* rjk, const int* pbatch,
    const float* z_emb, const float* e_feat, const float* pe_w1, const float* pe_b1,
    const float* pe_w2, const float* pe_w3,
    const float* h_flat, const float* gm_w1, const float* gm_w2, const float* gm_w3,
    float* ws, int* wsi)
{
    __shared__ float cwL[256];
    __shared__ int bL[256];
    __shared__ int redC[256];
    __shared__ float embL[4 * 32];
    int blkAll = blockIdx.x, t = threadIdx.x;
    if (blkAll < 32) {
        int bi = blkAll;
        for (int i = t; i < 2560; i += 256) ws[AGG_OFF + bi*2560 + i] = 0.f;
        int p = bi*250 + t;
        float cw = 0.f; int bin = -1; int valid = 0;
        if (t < 250) {
            cw = cutoff_fn(r0j[p]) * cutoff_fn(r0k[p]) * cutoff_fn(rjk[p]);
            ws[CW_OFF + p] = cw;
            bin = pbatch[p];
            valid = (cw > 0.f) ? 1 : 0;
        }
        cwL[t] = cw; bL[t] = bin; redC[t] = valid;
        __syncthreads();
        if (t < 16) {
            float s = 0.f; int c2 = 0;
            for (int i = 0; i < 256; ++i) {
                bool m = (bL[i] == t);
                s += m ? cwL[i] : 0.f;
                c2 += (m && cwL[i] > 0.f) ? 1 : 0;
            }
            ws[BSUM_OFF + bi*16 + t] = s;
            wsi[BCNTB_OFF + bi*16 + t] = c2;
        }
        __syncthreads();
        for (int s = 128; s > 0; s >>= 1) {
            if (t < s) redC[t] += redC[t + s];
            __syncthreads();
        }
        if (t == 0) wsi[BCNT_OFF + bi] = redC[0];
        return;
    }
    if (blkAll >= 106) {
        int blk = blkAll - 106;
        if (blk < 32) {            // h_flat split
            u16* hh = (u16*)(ws + HHI_OFF);
            u16* hl = (u16*)(ws + HLO_OFF);
            int base = blk * 4096;
            for (int idx = t; idx < 4096; idx += 256) {
                int e = base + idx;
                float v = h_flat[e];
                u16 h = f2bf_rne(v);
                hh[e] = h;
                hl[e] = f2bf_rne(v - __uint_as_float(((unsigned)h) << 16));
            }
        } else if (blk < 34) {     // gm_w1jk^T (256x128)
            u16* wh = (u16*)(ws + GW1JKH_OFF);
            u16* wl = (u16*)(ws + GW1JKL_OFF);
            int base = (blk - 32) * 16384;
            for (int idx = t; idx < 16384; idx += 256) {
                int e = base + idx;
                int m = e >> 7, k = e & 127;
                float v = gm_w1[((m < 128) ? k : (128 + k)) * 128 + (m & 127)];
                u16 h = f2bf_rne(v);
                wh[e] = h;
                wl[e] = f2bf_rne(v - __uint_as_float(((unsigned)h) << 16));
            }
        } else if (blk == 34) {    // gm_w1rbf^T (128x128, k<97)
            u16* wh = (u16*)(ws + GW1RH_OFF);
            u16* wl = (u16*)(ws + GW1RL_OFF);
            for (int e = t; e < 16384; e += 256) {
                int m = e >> 7, k = e & 127;
                float v = (k < 97) ? gm_w1[(256 + k) * 128 + m] : 0.f;
                u16 h = f2bf_rne(v);
                wh[e] = h;
                wl[e] = f2bf_rne(v - __uint_as_float(((unsigned)h) << 16));
            }
        } else if (blk == 35) {    // gm_w2^T
            u16* wh = (u16*)(ws + GW2H_OFF);
            u16* wl = (u16*)(ws + GW2L_OFF);
            for (int e = t; e < 16384; e += 256) {
                int m = e >> 7, k = e & 127;
                float v = gm_w2[k * 128 + m];
                u16 h = f2bf_rne(v);
                wh[e] = h;
                wl[e] = f2bf_rne(v - __uint_as_float(((unsigned)h) << 16));
            }
        } else {                   // gm_w3^T (64x128)
            u16* wh = (u16*)(ws + GW3H_OFF);
            u16* wl = (u16*)(ws + GW3L_OFF);
            for (int e = t; e < 8192; e += 256) {
                int m = e >> 7, k = e & 127;
                float v = gm_w3[k * 64 + m];
                u16 h = f2bf_rne(v);
                wh[e] = h;
                wl[e] = f2bf_rne(v - __uint_as_float(((unsigned)h) << 16));
            }
        }
        return;
    }
    int blk = blkAll - 32;
    if (blk >= 72) {
        const float* W = (blk == 72) ? pe_w2 : pe_w3;
        u16* hiD = (u16*)(ws + ((blk == 72) ? W2THI_OFF : W3THI_OFF));
        u16* loD = (u16*)(ws + ((blk == 72) ? W2TLO_OFF : W3TLO_OFF));
        for (int idx = t; idx < 4096; idx += 256) {
            int k = idx >> 6, n = idx & 63;
            float v = W[idx];
            u16 h = f2bf_rne(v);
            float hf = __uint_as_float(((unsigned)h) << 16);
            hiD[n*64 + k] = h;
            loD[n*64 + k] = f2bf_rne(v - hf);
        }
        return;
    }
    int r0, nrows, wbase;
    const float* src;
    float* dst;
    bool addb = false;
    if (blk < 26)      { r0 = blk * 4;        nrows = 101; src = z_emb;  wbase = 0;  dst = ws + ZEJW_OFF; }
    else if (blk < 52) { r0 = (blk - 26) * 4; nrows = 101; src = z_emb;  wbase = 32; dst = ws + ZEKW_OFF; }
    else               { r0 = (blk - 52) * 4; nrows = NEE; src = e_feat; wbase = 64; dst = ws + EFWB_OFF; addb = true; }
    if (t < 128) {
        int rl = t >> 5, i = t & 31;
        int r = r0 + rl;
        embL[t] = (r < nrows) ? src[r * 32 + i] : 0.f;
    }
    __syncthreads();
    int rl = t >> 6, c = t & 63;
    float acc = addb ? pe_b1[c] : 0.f;
    #pragma unroll
    for (int i = 0; i < 32; ++i)
        acc = fmaf(embL[rl * 32 + i], pe_w1[(wbase + i) * 64 + c], acc);
    int r = r0 + rl;
    if (r < nrows) dst[r * 64 + c] = acc;
}

// ---------------- K0b: parallel scans, norm, chunk table (1 block, 256 thr)
__global__ __launch_bounds__(256) void k0b(float* ws, int* wsi)
{
    __shared__ int bcntL[32];
    __shared__ int cntB[16];
    __shared__ int boff[17];
    __shared__ int chkoff[17];
    int t = threadIdx.x;
    if (t < 16) {
        float s = 0.f;
        #pragma unroll 4
        for (int bi = 0; bi < 32; ++bi) s += ws[BSUM_OFF + bi*16 + t];
        ws[NORM_OFF + t] = s;
    }
    if (t >= 32 && t < 48) {
        int b = t - 32;
        int cb = 0;
        #pragma unroll 4
        for (int bi = 0; bi < 32; ++bi) cb += wsi[BCNTB_OFF + bi*16 + b];
        cntB[b] = cb;
    }
    if (t >= 64 && t < 96) bcntL[t - 64] = wsi[BCNT_OFF + (t - 64)];
    __syncthreads();
    for (int off = 1; off < 32; off <<= 1) {
        int v = (t < 32 && t >= off) ? bcntL[t - off] : 0;
        __syncthreads();
        if (t < 32) bcntL[t] += v;
        __syncthreads();
    }
    if (t < 32) wsi[BLKOFF_OFF + t] = bcntL[t] - wsi[BCNT_OFF + t];
    if (t == 0) {
        wsi[BLKOFF_OFF + 32] = bcntL[31];
        int bo = 0, co = 0;
        for (int b = 0; b < 16; ++b) {
            boff[b] = bo; chkoff[b] = co;
            bo += cntB[b];
            co += (cntB[b] + 31) >> 5;
        }
        boff[16] = bo; chkoff[16] = co;
        wsi[NC_OFF] = co;
    }
    __syncthreads();
    int NCv = chkoff[16];
    for (int ci = t; ci < NCv; ci += 256) {
        int b = 0;
        while (chkoff[b + 1] <= ci) b++;
        int local = ci - chkoff[b];
        int rem = cntB[b] - local * 32;
        wsi[CHS_OFF + ci] = boff[b] + local * 32;
        wsi[CHC_OFF + ci] = (rem < 32) ? rem : 32;
        wsi[CHB_OFF + ci] = b;
    }
}

// ---------------- K0c (blocks 0..31) + K1b (blocks 32..47) merged
__global__ __launch_bounds__(256) void k0c_k1b(
    const int* pj, const int* pk, const int* zf, float* ws, int* wsi)
{
    __shared__ int sc[256];
    int blk = blockIdx.x, t = threadIdx.x;
    if (blk < 32) {
        int bi = blk;
        int p = bi*250 + t;
        int valid = (t < 250 && ws[CW_OFF + p] > 0.f) ? 1 : 0;
        sc[t] = valid;
        __syncthreads();
        for (int off = 1; off < 256; off <<= 1) {
            int v = (t >= off) ? sc[t - off] : 0;
            __syncthreads();
            sc[t] += v;
            __syncthreads();
        }
        if (valid) {
            int pos = wsi[BLKOFF_OFF + bi] + sc[t] - 1;
            int pjv = pj[p], pkv = pk[p];
            wsi[AIDX_OFF + pos] = p;
            wsi[ZJA_OFF + pos] = zf[pjv];
            wsi[ZKA_OFF + pos] = zf[pkv];
            wsi[PJA_OFF + pos] = pjv;
            wsi[PKA_OFF + pos] = pkv;
            ws[CWA_OFF + pos] = ws[CW_OFF + p];
        }
        return;
    }
    // ---- k1b: hjW/hkW = [W1j;W1k]^T @ h^T via MFMA
    int a0 = (blk - 32) * 64;
    int lane = t & 63, w = t >> 6, c = lane & 15, g = lane >> 4;
    const u16* hh = (const u16*)(ws + HHI_OFF);
    const u16* hl = (const u16*)(ws + HLO_OFF);
    const u16* wh = (const u16*)(ws + GW1JKH_OFF);
    const u16* wl = (const u16*)(ws + GW1JKL_OFF);
    f32x4 acc[4][4];
    #pragma unroll
    for (int i = 0; i < 4; ++i)
        #pragma unroll
        for (int j = 0; j < 4; ++j) acc[i][j] = (f32x4){0.f, 0.f, 0.f, 0.f};
    #pragma unroll 1
    for (int ks = 0; ks < 4; ++ks) {
        bf16x8 Ah[4], Al[4], Bh[4], Bl[4];
        #pragma unroll
        for (int mt = 0; mt < 4; ++mt) {
            int off = (w * 64 + mt * 16 + c) * 128 + ks * 32 + g * 8;
            Ah[mt] = *(const bf16x8*)(wh + off);
            Al[mt] = *(const bf16x8*)(wl + off);
        }
        #pragma unroll
        for (int nt = 0; nt < 4; ++nt) {
            int off = (a0 + nt * 16 + c) * 128 + ks * 32 + g * 8;
            Bh[nt] = *(const bf16x8*)(hh + off);
            Bl[nt] = *(const bf16x8*)(hl + off);
        }
        #pragma unroll
        for (int mt = 0; mt < 4; ++mt)
            #pragma unroll
            for (int nt = 0; nt < 4; ++nt) {
                f32x4 d = acc[mt][nt];
                d = __builtin_amdgcn_mfma_f32_16x16x32_bf16(Ah[mt], Bh[nt], d, 0, 0, 0);
                d = __builtin_amdgcn_mfma_f32_16x16x32_bf16(Ah[mt], Bl[nt], d, 0, 0, 0);
                d = __builtin_amdgcn_mfma_f32_16x16x32_bf16(Al[mt], Bh[nt], d, 0, 0, 0);
                acc[mt][nt] = d;
            }
    }
    float* dst = ws + ((w < 2) ? HJW_OFF : HKW_OFF);
    #pragma unroll
    for (int mt = 0; mt < 4; ++mt)
        #pragma unroll
        for (int nt = 0; nt < 4; ++nt) {
            int m = (w & 1) * 64 + mt * 16 + g * 4;
            int a = a0 + nt * 16 + c;
            *(f32x4*)(dst + a * 128 + m) = acc[mt][nt];
        }
}

// ---------------- K2: geom MLP via MFMA (unchanged)
__global__ __launch_bounds__(256) void k2_geom_mfma(
    const float* r0jG, const float* r0kG, const float* rjkG, const float* cosG,
    const float* b1g, const float* b2g, const float* b3g,
    float* ws, const int* wsi, float* gcw)
{
    __shared__ __align__(16) float sum3L[32 * 128];
    __shared__ __align__(16) u16 rbfH[4096], rbfL[4096];
    __shared__ __align__(16) u16 h1H[4096], h1L[4096];
    __shared__ __align__(16) u16 h2H[4096], h2L[4096];
    __shared__ int pjS[32], pkS[32];
    __shared__ float cwS[32], r0jS[32], r0kS[32], rjkS[32], cosS[32];

    int NC = wsi[NC_OFF];
    int cid = blockIdx.x;
    if (cid >= NC) return;
    int cs = wsi[CHS_OFF + cid], cnt = wsi[CHC_OFF + cid];
    int t = threadIdx.x, lane = t & 63, w = t >> 6, c = lane & 15, g = lane >> 4;

    if (t < 32) {
        int ap = cs + min(t, cnt - 1);
        int a = wsi[AIDX_OFF + ap];
        pjS[t] = wsi[PJA_OFF + ap]; pkS[t] = wsi[PKA_OFF + ap];
        cwS[t] = ws[CWA_OFF + ap];
        r0jS[t] = r0jG[a]; r0kS[t] = r0kG[a]; rjkS[t] = rjkG[a]; cosS[t] = cosG[a];
    }
    __syncthreads();
    {
        int p = t >> 3, kc = (t & 7) * 16;
        const float* rj = ws + HJW_OFF + pjS[p] * 128 + kc;
        const float* rk = ws + HKW_OFF + pkS[p] * 128 + kc;
        #pragma unroll
        for (int q = 0; q < 4; ++q) {
            f32x4 v = *(const f32x4*)(rj + q * 4) + *(const f32x4*)(rk + q * 4);
            *(f32x4*)(sum3L + ((p * 128 + kc + q * 4) ^ ((p & 7) << 2))) = v;
        }
    }
    {
        int p = t >> 3, k0 = (t & 7) * 16;
        float r0jv = r0jS[p], r0kv = r0kS[p], rjkv = rjkS[p], cv = cosS[p];
        #pragma unroll
        for (int hf = 0; hf < 2; ++hf) {
            int kb = k0 + hf * 8;
            float xs[8];
            #pragma unroll
            for (int i = 0; i < 8; ++i) {
                int k = kb + i;
                float v;
                if (k < 32) v = rbff(r0jv, k);
                else if (k < 64) v = rbff(r0kv, k - 32);
                else if (k < 96) v = rbff(rjkv, k - 64);
                else if (k == 96) v = cv;
                else v = 0.f;
                xs[i] = v;
            }
            bf16x8 hi, lo;
            splitpack8(xs, hi, lo);
            int idx = (p * 128 + kb) ^ ((p & 7) << 3);
            *(bf16x8*)(rbfH + idx) = hi;
            *(bf16x8*)(rbfL + idx) = lo;
        }
    }
    __syncthreads();

    const u16* w1h = (const u16*)(ws + GW1RH_OFF);
    const u16* w1l = (const u16*)(ws + GW1RL_OFF);
    const u16* w2h = (const u16*)(ws + GW2H_OFF);
    const u16* w2l = (const u16*)(ws + GW2L_OFF);
    const u16* w3h = (const u16*)(ws + GW3H_OFF);
    const u16* w3l = (const u16*)(ws + GW3L_OFF);

    f32x4 acc[2][2];
    #pragma unroll
    for (int i = 0; i < 2; ++i)
        #pragma unroll
        for (int j = 0; j < 2; ++j) acc[i][j] = (f32x4){0.f, 0.f, 0.f, 0.f};
    #pragma unroll 1
    for (int ks = 0; ks < 4; ++ks) {
        bf16x8 Ah[2], Al[2], Bh[2], Bl[2];
        #pragma unroll
        for (int ml = 0; ml < 2; ++ml) {
            int off = ((w * 2 + ml) * 16 + c) * 128 + ks * 32 + g * 8;
            Ah[ml] = *(const bf16x8*)(w1h + off);
            Al[ml] = *(const bf16x8*)(w1l + off);
        }
        #pragma unroll
        for (int nt = 0; nt < 2; ++nt) {
            int p = nt * 16 + c;
            int idx = (p * 128 + ks * 32 + g * 8) ^ ((p & 7) << 3);
            Bh[nt] = *(const bf16x8*)(rbfH + idx);
            Bl[nt] = *(const bf16x8*)(rbfL + idx);
        }
        #pragma unroll
        for (int ml = 0; ml < 2; ++ml)
            #pragma unroll
            for (int nt = 0; nt < 2; ++nt) {
                f32x4 d = acc[ml][nt];
                d = __builtin_amdgcn_mfma_f32_16x16x32_bf16(Ah[ml], Bh[nt], d, 0, 0, 0);
                d = __builtin_amdgcn_mfma_f32_16x16x32_bf16(Ah[ml], Bl[nt], d, 0, 0, 0);
                d = __builtin_amdgcn_mfma_f32_16x16x32_bf16(Al[ml], Bh[nt], d, 0, 0, 0);
                acc[ml][nt] = d;
            }
    }
    #pragma unroll
    for (int ml = 0; ml < 2; ++ml)
        #pragma unroll
        for (int nt = 0; nt < 2; ++nt) {
            int p = nt * 16 + c;
            int m0 = (w * 2 + ml) * 16 + g * 4;
            f32x4 s = *(const f32x4*)(sum3L + ((p * 128 + m0) ^ ((p & 7) << 2)));
            f32x4 bb = *(const f32x4*)(b1g + m0);
            f32x4 x = acc[ml][nt] + s + bb;
            float v0 = siluf(x[0]), v1 = siluf(x[1]), v2 = siluf(x[2]), v3 = siluf(x[3]);
            unsigned h01 = cvtpk2(v0, v1), h23 = cvtpk2(v2, v3);
            float l0 = v0 - __uint_as_float(h01 << 16);
            float l1 = v1 - __uint_as_float(h01 & 0xFFFF0000u);
            float l2 = v2 - __uint_as_float(h23 << 16);
            float l3 = v3 - __uint_as_float(h23 & 0xFFFF0000u);
            unsigned lo01 = cvtpk2(l0, l1), lo23 = cvtpk2(l2, l3);
            int idx = (p * 128 + m0) ^ ((p & 7) << 3);
            uint2 uh; uh.x = h01; uh.y = h23;
            uint2 ul; ul.x = lo01; ul.y = lo23;
            *(uint2*)(h1H + idx) = uh;
            *(uint2*)(h1L + idx) = ul;
        }
    __syncthreads();

    #pragma unroll
    for (int i = 0; i < 2; ++i)
        #pragma unroll
        for (int j = 0; j < 2; ++j) acc[i][j] = (f32x4){0.f, 0.f, 0.f, 0.f};
    #pragma unroll 1
    for (int ks = 0; ks < 4; ++ks) {
        bf16x8 Ah[2], Al[2], Bh[2], Bl[2];
        #pragma unroll
        for (int ml = 0; ml < 2; ++ml) {
            int off = ((w * 2 + ml) * 16 + c) * 128 + ks * 32 + g * 8;
            Ah[ml] = *(const bf16x8*)(w2h + off);
            Al[ml] = *(const bf16x8*)(w2l + off);
        }
        #pragma unroll
        for (int nt = 0; nt < 2; ++nt) {
            int p = nt * 16 + c;
            int idx = (p * 128 + ks * 32 + g * 8) ^ ((p & 7) << 3);
            Bh[nt] = *(const bf16x8*)(h1H + idx);
            Bl[nt] = *(const bf16x8*)(h1L + idx);
        }
        #pragma unroll
        for (int ml = 0; ml < 2; ++ml)
            #pragma unroll
            for (int nt = 0; nt < 2; ++nt) {
                f32x4 d = acc[ml][nt];
                d = __builtin_amdgcn_mfma_f32_16x16x32_bf16(Ah[ml], Bh[nt], d, 0, 0, 0);
                d = __builtin_amdgcn_mfma_f32_16x16x32_bf16(Ah[ml], Bl[nt], d, 0, 0, 0);
                d = __builtin_amdgcn_mfma_f32_16x16x32_bf16(Al[ml], Bh[nt], d, 0, 0, 0);
                acc[ml][nt] = d;
            }
    }
    #pragma unroll
    for (int ml = 0; ml < 2; ++ml)
        #pragma unroll
        for (int nt = 0; nt < 2; ++nt) {
            int p = nt * 16 + c;
            int m0 = (w * 2 + ml) * 16 + g * 4;
            f32x4 bb = *(const f32x4*)(b2g + m0);
            f32x4 x = acc[ml][nt] + bb;
            float v0 = siluf(x[0]), v1 = siluf(x[1]), v2 = siluf(x[2]), v3 = siluf(x[3]);
            unsigned h01 = cvtpk2(v0, v1), h23 = cvtpk2(v2, v3);
            float l0 = v0 - __uint_as_float(h01 << 16);
            float l1 = v1 - __uint_as_float(h01 & 0xFFFF0000u);
            float l2 = v2 - __uint_as_float(h23 << 16);
            float l3 = v3 - __uint_as_float(h23 & 0xFFFF0000u);
            unsigned lo01 = cvtpk2(l0, l1), lo23 = cvtpk2(l2, l3);
            int idx = (p * 128 + m0) ^ ((p & 7) << 3);
            uint2 uh; uh.x = h01; uh.y = h23;
            uint2 ul; ul.x = lo01; ul.y = lo23;
            *(uint2*)(h2H + idx) = uh;
            *(uint2*)(h2L + idx) = ul;
        }
    __syncthreads();

    f32x4 acc3[2];
    acc3[0] = (f32x4){0.f, 0.f, 0.f, 0.f};
    acc3[1] = (f32x4){0.f, 0.f, 0.f, 0.f};
    #pragma unroll 1
    for (int ks = 0; ks < 4; ++ks) {
        bf16x8 Ah, Al, Bh[2], Bl[2];
        {
            int off = (w * 16 + c) * 128 + ks * 32 + g * 8;
            Ah = *(const bf16x8*)(w3h + off);
            Al = *(const bf16x8*)(w3l + off);
        }
        #pragma unroll
        for (int nt = 0; nt < 2; ++nt) {
            int p = nt * 16 + c;
            int idx = (p * 128 + ks * 32 + g * 8) ^ ((p & 7) << 3);
            Bh[nt] = *(const bf16x8*)(h2H + idx);
            Bl[nt] = *(const bf16x8*)(h2L + idx);
        }
        #pragma unroll
        for (int nt = 0; nt < 2; ++nt) {
            f32x4 d = acc3[nt];
            d = __builtin_amdgcn_mfma_f32_16x16x32_bf16(Ah, Bh[nt], d, 0, 0, 0);
            d = __builtin_amdgcn_mfma_f32_16x16x32_bf16(Ah, Bl[nt], d, 0, 0, 0);
            d = __builtin_amdgcn_mfma_f32_16x16x32_bf16(Al, Bh[nt], d, 0, 0, 0);
            acc3[nt] = d;
        }
    }
    {
        int m0 = w * 16 + g * 4;
        f32x4 bb = *(const f32x4*)(b3g + m0);
        #pragma unroll
        for (int nt = 0; nt < 2; ++nt) {
            int p = nt * 16 + c;
            if (p < cnt) {
                f32x4 o = (acc3[nt] + bb) * cwS[p];
                *(f32x4*)(gcw + (cs + p) * 64 + m0) = o;
            }
        }
    }
}

// ---------------- K3: pair MLP via MFMA — 8 e/block (2/wave), hoisted addresses
// LDS 40960: sL 8K + h2buf 16K + a2lL 8K + a3lL 8K. Grid 266*10.
__global__ __launch_bounds__(256) void k3_pair_mfma(
    const float* ws, const int* wsi, const float* gcw, float* agg,
    const float* b2g, const float* b3g)
{
    __shared__ __align__(16) float sL[32 * 64];      // 8KB
    __shared__ __align__(16) u16 h2buf[4][2048];     // 16KB (per wave: hi[0..1023], lo[1024..2047])
    __shared__ __align__(16) u16 a2lL[4096];         // 8KB  W2^T lo plane (swizzled)
    __shared__ __align__(16) u16 a3lL[4096];         // 8KB  W3^T lo plane (swizzled)

    int NC = wsi[NC_OFF];
    int bid = blockIdx.x;
    int cid = bid / 10;
    int et  = bid - cid * 10;
    if (cid >= NC) return;
    int cs  = wsi[CHS_OFF + cid];
    int cnt = wsi[CHC_OFF + cid];
    int bb  = wsi[CHB_OFF + cid];

    int t = threadIdx.x;
    int lane = t & 63, w = t >> 6;
    int c = lane & 15, g = lane >> 4;

    // stage sL (swizzled f32)
    {
        int p = t >> 3, kc = (t & 7) * 8;
        int ap = cs + min(p, cnt - 1);
        int zj = wsi[ZJA_OFF + ap], zk = wsi[ZKA_OFF + ap];
        const f32x4* rj = (const f32x4*)(ws + ZEJW_OFF + zj * 64 + kc);
        const f32x4* rk = (const f32x4*)(ws + ZEKW_OFF + zk * 64 + kc);
        int sw = (p & 7) << 2;
        *(f32x4*)(sL + ((p * 64 + kc) ^ sw))     = rj[0] + rk[0];
        *(f32x4*)(sL + ((p * 64 + kc + 4) ^ sw)) = rj[1] + rk[1];
    }
    // stage lo-planes of W2^T/W3^T into LDS with row-swizzle
    {
        const unsigned* s2 = (const unsigned*)(ws + W2TLO_OFF);
        const unsigned* s3 = (const unsigned*)(ws + W3TLO_OFF);
        unsigned* d2 = (unsigned*)a2lL;
        unsigned* d3 = (unsigned*)a3lL;
        #pragma unroll
        for (int rr = 0; rr < 8; ++rr) {
            int i = rr * 256 + t;
            int sw = ((i >> 5) & 7) << 2;
            d2[i ^ sw] = s2[i];
            d3[i ^ sw] = s3[i];
        }
    }
    // hi-plane A fragments resident in regs
    const u16* w2hi = (const u16*)(ws + W2THI_OFF);
    const u16* w3hi = (const u16*)(ws + W3THI_OFF);
    bf16x8 A2h[4][2], A3h[4][2];
    #pragma unroll
    for (int mt = 0; mt < 4; ++mt)
        #pragma unroll
        for (int ks = 0; ks < 2; ++ks) {
            int off = (mt * 16 + c) * 64 + ks * 32 + g * 8;
            A2h[mt][ks] = *(const bf16x8*)(w2hi + off);
            A3h[mt][ks] = *(const bf16x8*)(w3hi + off);
        }
    __syncthreads();

    u16* myh = h2buf[w];
    u16* myl = h2buf[w] + 1024;
    const float* efp = ws + EFWB_OFF;
    const int aswz = (c & 7) << 3;   // u16-space swizzle, bits 3..5

    // Hoisted per-lane swizzled sub-offsets (XOR split into disjoint bit fields):
    // weight-lo arrays: addr = mt*1024 + c*64 + wk[ks],  wk[ks] = (ks*32 + g*8) ^ aswz
    const int cb64 = c * 64;
    const int wk0 = (g * 8) ^ aswz;
    const int wk1 = (32 + g * 8) ^ aswz;
    // h2buf write: idx = c*64 + (mt*16 ^ s48) + (4g ^ s8)
    const int s48 = aswz & 48, s8 = aswz & 8;
    const int hwb = cb64 + ((4 * g) ^ s8);
    // h2buf read: idx = c*64 + wk[ks]  (same formula as weight arrays)
    const u16* a2p = a2lL + cb64;
    const u16* a3p = a3lL + cb64;

    #pragma unroll 1
    for (int ei = 0; ei < 2; ++ei) {
        int e = et * 8 + w * 2 + ei;
        float part[16];
        #pragma unroll
        for (int i = 0; i < 16; ++i) part[i] = 0.f;

        #pragma unroll 1
        for (int nt = 0; nt < 2; ++nt) {
            int p = nt * 16 + c;
            int psw = (p & 7) << 2;
            // ---- prefetch gcw contrib rows (consumed at end of nt body)
            f32x4 gvr[4];
            {
                int pc = cs + min(p, cnt - 1);
                #pragma unroll
                for (int mt = 0; mt < 4; ++mt)
                    gvr[mt] = *(const f32x4*)(gcw + pc * 64 + mt * 16 + 4 * g);
            }
            f32x4 acc4[4];
            #pragma unroll
            for (int mt = 0; mt < 4; ++mt) acc4[mt] = (f32x4){0.f, 0.f, 0.f, 0.f};
            // ---- layer 2
            #pragma unroll
            for (int ks = 0; ks < 2; ++ks) {
                f32x4 e0 = *(const f32x4*)(efp + e * 64 + ks * 32 + g * 8);
                f32x4 e1 = *(const f32x4*)(efp + e * 64 + ks * 32 + g * 8 + 4);
                int base = p * 64 + ks * 32 + g * 8;
                f32x4 x0 = *(const f32x4*)(sL + (base ^ psw));
                f32x4 x1 = *(const f32x4*)(sL + ((base + 4) ^ psw));
                x0 += e0; x1 += e1;
                float xs[8];
                #pragma unroll
                for (int i = 0; i < 4; ++i) { xs[i] = siluf(x0[i]); xs[4 + i] = siluf(x1[i]); }
                bf16x8 Bh, Bl;
                splitpack8(xs, Bh, Bl);
                const int wk = ks ? wk1 : wk0;
                #pragma unroll
                for (int mt = 0; mt < 4; ++mt) {
                    bf16x8 a2l = *(const bf16x8*)(a2p + wk + mt * 1024);
                    f32x4 d = acc4[mt];
                    d = __builtin_amdgcn_mfma_f32_16x16x32_bf16(A2h[mt][ks], Bh, d, 0, 0, 0);
                    d = __builtin_amdgcn_mfma_f32_16x16x32_bf16(A2h[mt][ks], Bl, d, 0, 0, 0);
                    d = __builtin_amdgcn_mfma_f32_16x16x32_bf16(a2l,         Bh, d, 0, 0, 0);
                    acc4[mt] = d;
                }
            }
            // ---- h2 = silu(acc+b2) -> per-wave LDS roundtrip (bf16 hi/lo)
            #pragma unroll
            for (int mt = 0; mt < 4; ++mt) {
                f32x4 b2v = *(const f32x4*)(b2g + mt * 16 + 4 * g);
                f32x4 h = acc4[mt] + b2v;
                float v0 = siluf(h[0]), v1 = siluf(h[1]), v2 = siluf(h[2]), v3 = siluf(h[3]);
                unsigned h01 = cvtpk2(v0, v1), h23 = cvtpk2(v2, v3);
                float l0 = v0 - __uint_as_float(h01 << 16);
                float l1 = v1 - __uint_as_float(h01 & 0xFFFF0000u);
                float l2 = v2 - __uint_as_float(h23 << 16);
                float l3 = v3 - __uint_as_float(h23 & 0xFFFF0000u);
                unsigned lo01 = cvtpk2(l0, l1), lo23 = cvtpk2(l2, l3);
                int idx = hwb + ((mt * 16) ^ s48);
                uint2 uh, ul;
                uh.x = h01; uh.y = h23;
                ul.x = lo01; ul.y = lo23;
                *(uint2*)(myh + idx) = uh;
                *(uint2*)(myl + idx) = ul;
                acc4[mt] = (f32x4){0.f, 0.f, 0.f, 0.f};   // reuse as L3 accumulator
            }
            // ---- layer 3
            #pragma unroll
            for (int ks = 0; ks < 2; ++ks) {
                const int wk = ks ? wk1 : wk0;
                bf16x8 Ch = *(const bf16x8*)(myh + cb64 + wk);
                bf16x8 Cl = *(const bf16x8*)(myl + cb64 + wk);
                #pragma unroll
                for (int mt = 0; mt < 4; ++mt) {
                    bf16x8 a3l = *(const bf16x8*)(a3p + wk + mt * 1024);
                    f32x4 d = acc4[mt];
                    d = __builtin_amdgcn_mfma_f32_16x16x32_bf16(A3h[mt][ks], Ch, d, 0, 0, 0);
                    d = __builtin_amdgcn_mfma_f32_16x16x32_bf16(A3h[mt][ks], Cl, d, 0, 0, 0);
                    d = __builtin_amdgcn_mfma_f32_16x16x32_bf16(a3l,         Ch, d, 0, 0, 0);
                    acc4[mt] = d;
                }
            }
            // ---- contrib (gvr prefetched; zero masked for tail paths)
            float vmask = (p < cnt) ? 1.f : 0.f;
            #pragma unroll
            for (int mt = 0; mt < 4; ++mt) {
                f32x4 b3v = *(const f32x4*)(b3g + mt * 16 + 4 * g);
                f32x4 o = acc4[mt] + b3v;
                #pragma unroll
                for (int r = 0; r < 4; ++r) part[mt * 4 + r] += o[r] * gvr[mt][r] * vmask;
            }
        }
        // ---- reduce over the 16 c-lanes via butterfly, 1 atomic per lane
        #pragma unroll
        for (int i = 0; i < 16; ++i) {
            float v = part[i];
            v += __shfl_xor(v, 1, 64);
            v += __shfl_xor(v, 2, 64);
            v += __shfl_xor(v, 4, 64);
            v += __shfl_xor(v, 8, 64);
            part[i] = v;
        }
        int f = (c >> 2) * 16 + g * 4 + (c & 3);
        atomicAdd(agg + (bb * NEE + e) * 64 + f, part[c]);
    }
}

// ---------------- K4: normalize + out MLP (64->128->64)
__global__ __launch_bounds__(256) void k4_out(
    const float* ws, const float* W1, const float* b1,
    const float* W2, const float* b2, float* out)
{
    __shared__ float xT[64][68];
    __shared__ float W1L[64 * 128];
    __shared__ float hTT[128][68];
    __shared__ float W2L[128 * 64];
    __shared__ float normL[16];
    int t = threadIdx.x;
    int gbase = blockIdx.x * 64;
    if (t < 16) normL[t] = 1.f / fmaxf(ws[NORM_OFF + t], 1e-8f);
    for (int idx = t; idx < 8192; idx += 256) { W1L[idx] = W1[idx]; W2L[idx] = W2[idx]; }
    __syncthreads();
    {
        int r = t & 63, cq = t >> 6;
        int gg = gbase + r;
        int b = gg / NEE;
        float rn = normL[b];
        const float* arow = ws + AGG_OFF + gg * 64 + cq * 16;
        #pragma unroll
        for (int q = 0; q < 4; ++q) {
            float4 v = *(const float4*)(arow + q * 4);
            int c = cq * 16 + q * 4;
            xT[c + 0][r] = v.x * rn; xT[c + 1][r] = v.y * rn;
            xT[c + 2][r] = v.z * rn; xT[c + 3][r] = v.w * rn;
        }
    }
    __syncthreads();
    {
        int tcx = t & 15, trx = t >> 4;
        int c0 = tcx * 8, r0 = trx * 4;
        float acc[4][8];
        #pragma unroll
        for (int j = 0; j < 4; ++j)
            #pragma unroll
            for (int q = 0; q < 8; ++q) acc[j][q] = 0.f;
        #pragma unroll 4
        for (int kk = 0; kk < 64; ++kk) {
            float4 x4 = *(const float4*)&xT[kk][r0];
            float4 wa = *(const float4*)&W1L[kk * 128 + c0];
            float4 wb = *(const float4*)&W1L[kk * 128 + c0 + 4];
            float x[4] = {x4.x, x4.y, x4.z, x4.w};
            float w[8] = {wa.x, wa.y, wa.z, wa.w, wb.x, wb.y, wb.z, wb.w};
            #pragma unroll
            for (int j = 0; j < 4; ++j)
                #pragma unroll
                for (int q = 0; q < 8; ++q)
                    acc[j][q] = fmaf(x[j], w[q], acc[j][q]);
        }
        #pragma unroll
        for (int q = 0; q < 8; ++q) {
            float bb = b1[c0 + q];
            float4 v;
            v.x = siluf(acc[0][q] + bb);
            v.y = siluf(acc[1][q] + bb);
            v.z = siluf(acc[2][q] + bb);
            v.w = siluf(acc[3][q] + bb);
            *(float4*)&hTT[c0 + q][r0] = v;
        }
    }
    __syncthreads();
    {
        int tcx = t & 7, trx = t >> 3;
        int c0 = tcx * 8, r0 = trx * 2;
        float acc[2][8];
        #pragma unroll
        for (int j = 0; j < 2; ++j)
            #pragma unroll
            for (int q = 0; q < 8; ++q) acc[j][q] = 0.f;
        #pragma unroll 4
        for (int kk = 0; kk < 128; ++kk) {
            float2 x2 = *(const float2*)&hTT[kk][r0];
            float4 wa = *(const float4*)&W2L[kk * 64 + c0];
            float4 wb = *(const float4*)&W2L[kk * 64 + c0 + 4];
            float w[8] = {wa.x, wa.y, wa.z, wa.w, wb.x, wb.y, wb.z, wb.w};
            #pragma unroll
            for (int q = 0; q < 8; ++q) {
                acc[0][q] = fmaf(x2.x, w[q], acc[0][q]);
                acc[1][q] = fmaf(x2.y, w[q], acc[1][q]);
            }
        }
        int gg = gbase + r0;
        #pragma unroll
        for (int j = 0; j < 2; ++j) {
            float o[8];
            #pragma unroll
            for (int q = 0; q < 8; ++q) o[q] = acc[j][q] + b2[c0 + q];
            *(float4*)&out[(gg + j) * 64 + c0] = make_float4(o[0], o[1], o[2], o[3]);
            *(float4*)&out[(gg + j) * 64 + c0 + 4] = make_float4(o[4], o[5], o[6], o[7]);
        }
    }
}

extern "C" void kernel_launch(void* const* d_in, const int* in_sizes, int n_in,
                              void* d_out, int out_size, void* d_ws, size_t ws_size,
                              hipStream_t stream) {
    (void)in_sizes; (void)n_in; (void)out_size; (void)ws_size;
    const float* h_flat = (const float*)d_in[0];
    const int*   z_flat = (const int*)d_in[1];
    const float* e_feat = (const float*)d_in[2];
    const int*   path_j = (const int*)d_in[3];
    const int*   path_k = (const int*)d_in[4];
    const float* r0j    = (const float*)d_in[5];
    const float* r0k    = (const float*)d_in[6];
    const float* rjk    = (const float*)d_in[7];
    const float* cosang = (const float*)d_in[8];
    const int*   pbatch = (const int*)d_in[9];
    const float* z_emb  = (const float*)d_in[11];
    const float* pe_w1  = (const float*)d_in[12];
    const float* pe_b1  = (const float*)d_in[13];
    const float* pe_w2  = (const float*)d_in[14];
    const float* pe_b2  = (const float*)d_in[15];
    const float* pe_w3  = (const float*)d_in[16];
    const float* pe_b3  = (const float*)d_in[17];
    const float* gm_w1  = (const float*)d_in[18];
    const float* gm_b1  = (const float*)d_in[19];
    const float* gm_w2  = (const float*)d_in[20];
    const float* gm_b2  = (const float*)d_in[21];
    const float* gm_w3  = (const float*)d_in[22];
    const float* gm_b3  = (const float*)d_in[23];
    const float* op_w1  = (const float*)d_in[24];
    const float* op_b1  = (const float*)d_in[25];
    const float* op_w2  = (const float*)d_in[26];
    const float* op_b2  = (const float*)d_in[27];

    float* ws  = (float*)d_ws;
    int*   wsi = (int*)d_ws;
    float* gcw = ws + GCW_OFF;
    float* agg = ws + AGG_OFF;

    hipLaunchKernelGGL(k0a_k1, dim3(143), dim3(256), 0, stream,
                       r0j, r0k, rjk, pbatch,
                       z_emb, e_feat, pe_w1, pe_b1, pe_w2, pe_w3,
                       h_flat, gm_w1, gm_w2, gm_w3, ws, wsi);
    hipLaunchKernelGGL(k0b, dim3(1), dim3(256), 0, stream, ws, wsi);
    hipLaunchKernelGGL(k0c_k1b, dim3(48), dim3(256), 0, stream,
                       path_j, path_k, z_flat, ws, wsi);
    hipLaunchKernelGGL(k2_geom_mfma, dim3(266), dim3(256), 0, stream,
                       r0j, r0k, rjk, cosang,
                       gm_b1, gm_b2, gm_b3, ws, wsi, gcw);
    hipLaunchKernelGGL(k3_pair_mfma, dim3(2660), dim3(256), 0, stream,
                       ws, wsi, gcw, agg, pe_b2, pe_b3);
    hipLaunchKernelGGL(k4_out, dim3(20), dim3(256), 0, stream,
                       ws, op_w1, op_b1, op_w2, op_b2, (float*)d_out);
}